// Round 16
// baseline (1020.344 us; speedup 1.0000x reference)
//
#include <hip/hip_runtime.h>
#include <hip/hip_bf16.h>

// TSTEncoder: L=4 layers, D=512, H=8, FF=2048, B=32, S=512, DK=64
// Residual attention (raw scores carried across layers), post-norm, GELU.

#define NL 4
#define DMODEL 512
#define NH 8
#define FFDIM 2048
#define BATCH 32
#define SEQ 512
#define DHEAD 64
#define NTOK (BATCH*SEQ)          // 16384
#define LDQKV (3*DMODEL)          // 1536

typedef unsigned short u16;
typedef __bf16 bf16x8 __attribute__((ext_vector_type(8)));
typedef float f32x4 __attribute__((ext_vector_type(4)));
typedef unsigned short u16x8 __attribute__((ext_vector_type(8)));
typedef unsigned short u16x4 __attribute__((ext_vector_type(4)));

// f32 -> bf16 RNE via native cast (compiler emits v_cvt_pk_bf16_f32 for pairs)
__device__ __forceinline__ u16 f2b(float f){
  return __builtin_bit_cast(u16, (__bf16)f);
}
__device__ __forceinline__ float b2f(u16 h){
  return __builtin_bit_cast(float, ((unsigned)h)<<16);
}
__device__ __forceinline__ void gll16(const void* g, void* l){
  __builtin_amdgcn_global_load_lds((__attribute__((address_space(1))) void*)(g),
                                   (__attribute__((address_space(3))) void*)(l), 16, 0, 0);
}
__device__ __forceinline__ float wred_sum(float v){
  #pragma unroll
  for (int off=32; off; off>>=1) v += __shfl_xor(v, off, 64);
  return v;
}
// GELU, tanh form: 0.5v(1+tanh(0.79788456(v+0.044715v^3))) = v - v/(e^{2y}+1)
__device__ __forceinline__ float gelu_f(float v){
  float y = 0.79788456080286536f*(v + 0.044715f*v*v*v);
  float t = __expf(2.0f*y);
  return v - v/(t + 1.0f);
}

// ---------------- GEMM 128x128 (256 thr): C = A * Bt^T + bias ----------------
// BK=32, double-buffered LDS, T4 counted-vmcnt pipeline.
// OUT_MODE: 0 = bf16 store, 2 = GELU then bf16 store
template<int OUT_MODE>
__global__ __launch_bounds__(256) void gemm_bt(
    const u16* __restrict__ A, const u16* __restrict__ Bt,
    const float* __restrict__ bias, u16* __restrict__ Cout,
    int M, int N, int K)
{
  __shared__ u16 smem[16384];   // 2 bufs x (lA[128][32] + lB[128][32]) = 32 KB
  const int t = threadIdx.x;
  const int w = t>>6, lane = t&63;

  // XCD-chunked bijective swizzle (all grids divisible by 8)
  const int gx = gridDim.x;
  const int id = blockIdx.y*gx + blockIdx.x;
  const int cpx = (gx*gridDim.y) >> 3;
  const int nid = (id & 7)*cpx + (id >> 3);
  const int m0 = (nid / gx)*128, n0 = (nid % gx)*128;

  const int wr = (w>>1)*64, wc = (w&1)*64;

  f32x4 acc[4][4];
  #pragma unroll
  for (int m=0;m<4;m++)
    #pragma unroll
    for (int n=0;n<4;n++) acc[m][n] = f32x4{0.f,0.f,0.f,0.f};

  const int srow = t>>2;
  const int scol = (((t&3) ^ ((srow>>1)&3)))*8;
  const size_t aBase = (size_t)(m0 + srow)*K + scol;
  const size_t bBase = (size_t)(n0 + srow)*K + scol;
  const size_t rstep = (size_t)64*K;
  const int dstw = w*512;

  #define STAGE(buf, k0) do{                                       \
    u16* base_ = smem + (buf)*8192;                                \
    gll16(A  + aBase + (k0),          base_ + dstw);               \
    gll16(A  + aBase + rstep + (k0),  base_ + 2048 + dstw);        \
    gll16(Bt + bBase + (k0),          base_ + 4096 + dstw);        \
    gll16(Bt + bBase + rstep + (k0),  base_ + 6144 + dstw);        \
  }while(0)

  const int g = lane>>4, r16 = lane&15;
  const int chunkoff = ((g ^ ((r16>>1)&3))<<3);   // read-side XOR undoes source swizzle

  STAGE(0, 0);
  int cur = 0;
  for (int k0=0; k0<K; k0+=32){
    if (k0+32 < K){
      STAGE(cur^1, k0+32);
      asm volatile("s_waitcnt vmcnt(4)" ::: "memory");   // buf[cur] done; 4 stay in flight
    } else {
      asm volatile("s_waitcnt vmcnt(0)" ::: "memory");   // tail: drain the last tile
    }
    asm volatile("s_barrier" ::: "memory");
    const u16* lA = smem + cur*8192;
    const u16* lB = lA + 4096;
    bf16x8 af[4], bfr[4];
    #pragma unroll
    for (int m=0;m<4;m++) af[m]  = *(const bf16x8*)(lA + (wr+m*16+r16)*32 + chunkoff);
    #pragma unroll
    for (int n=0;n<4;n++) bfr[n] = *(const bf16x8*)(lB + (wc+n*16+r16)*32 + chunkoff);
    #pragma unroll
    for (int m=0;m<4;m++)
      #pragma unroll
      for (int n=0;n<4;n++)
        acc[m][n] = __builtin_amdgcn_mfma_f32_16x16x32_bf16(af[m], bfr[n], acc[m][n], 0,0,0);
    asm volatile("s_waitcnt lgkmcnt(0)" ::: "memory");   // my ds_reads of buf[cur] complete
    asm volatile("s_barrier" ::: "memory");              // all waves done reading buf[cur]
    cur ^= 1;
  }
  #undef STAGE

  // epilogue: 2 strips of 64 rows; stage u16 in LDS (swizzled) then coalesced 16B stores
  const int c16 = lane&15, r4 = (lane>>4)*4;
  float bb[4];
  #pragma unroll
  for (int n=0;n<4;n++) bb[n] = bias[n0 + wc + n*16 + c16];
  #pragma unroll
  for (int s=0;s<2;s++){
    __syncthreads();
    if ((w>>1)==s){
      #pragma unroll
      for (int m=0;m<4;m++)
        #pragma unroll
        for (int n=0;n<4;n++)
          #pragma unroll
          for (int j=0;j<4;j++){
            float val = acc[m][n][j] + bb[n];
            if (OUT_MODE==2) val = gelu_f(val);
            const int row = m*16 + r4 + j;
            const int col = (wc + n*16 + c16) ^ (((row>>2)&3)<<4);
            smem[row*128 + col] = f2b(val);
          }
    }
    __syncthreads();
    #pragma unroll
    for (int i=0;i<4;i++){
      const int lrow = i*16 + (t>>4), colr = (t&15)*8;
      u16x8 vv = *(const u16x8*)(smem + lrow*128 + (colr ^ (((lrow>>2)&3)<<4)));
      *(u16x8*)(Cout + (size_t)(m0 + s*64 + lrow)*N + n0 + colr) = vv;
    }
  }
}

// ---------------- GEMM 128x256 (512 thr, 8 waves): C = A * Bt^T + bias ----------------
// OUT_MODE: 0 = bf16, 2 = GELU+bf16, 3 = QKV mode (V-feature blocks n0>=1024 write
// vt[b,h,d,s] transposed directly from the LDS tile; q/k blocks store normally).
template<int OUT_MODE>
__global__ __launch_bounds__(512) void gemm_bt_wide(
    const u16* __restrict__ A, const u16* __restrict__ Bt,
    const float* __restrict__ bias, u16* __restrict__ Cout,
    u16* __restrict__ vtout,
    int M, int N, int K)
{
  __shared__ u16 smem[24576];   // 2 bufs x (lA[128][32]=8KB + lB[256][32]=16KB) = 48 KB
  const int t = threadIdx.x;
  const int w = t>>6, lane = t&63;

  const int gx = gridDim.x;
  const int id = blockIdx.y*gx + blockIdx.x;
  const int cpx = (gx*gridDim.y) >> 3;
  const int nid = (id & 7)*cpx + (id >> 3);
  const int m0 = (nid / gx)*128, n0 = (nid % gx)*256;

  const int wr = (w>>2)*64, wc = (w&3)*64;

  f32x4 acc[4][4];
  #pragma unroll
  for (int m=0;m<4;m++)
    #pragma unroll
    for (int n=0;n<4;n++) acc[m][n] = f32x4{0.f,0.f,0.f,0.f};

  const int srow = t>>2;
  const int scol = (((t&3) ^ ((srow>>1)&3)))*8;
  const size_t aBase = (size_t)(m0 + srow)*K + scol;
  const size_t bBase = (size_t)(n0 + srow)*K + scol;
  const size_t brstep = (size_t)128*K;    // B rows 128..255 (same XOR: 128%8==0)
  const int dstw = w*512;

  #define STAGEW(buf, k0) do{                                      \
    u16* base_ = smem + (buf)*12288;                               \
    gll16(A  + aBase + (k0),           base_ + dstw);              \
    gll16(Bt + bBase + (k0),           base_ + 4096 + dstw);       \
    gll16(Bt + bBase + brstep + (k0),  base_ + 8192 + dstw);       \
  }while(0)

  const int g = lane>>4, r16 = lane&15;
  const int chunkoff = ((g ^ ((r16>>1)&3))<<3);

  STAGEW(0, 0);
  int cur = 0;
  for (int k0=0; k0<K; k0+=32){
    if (k0+32 < K){
      STAGEW(cur^1, k0+32);
      asm volatile("s_waitcnt vmcnt(3)" ::: "memory");   // buf[cur]'s 3 loads done; 3 in flight
    } else {
      asm volatile("s_waitcnt vmcnt(0)" ::: "memory");
    }
    asm volatile("s_barrier" ::: "memory");
    const u16* lA = smem + cur*12288;
    const u16* lB = lA + 4096;
    bf16x8 af[4], bfr[4];
    #pragma unroll
    for (int m=0;m<4;m++) af[m]  = *(const bf16x8*)(lA + (wr+m*16+r16)*32 + chunkoff);
    #pragma unroll
    for (int n=0;n<4;n++) bfr[n] = *(const bf16x8*)(lB + (wc+n*16+r16)*32 + chunkoff);
    #pragma unroll
    for (int m=0;m<4;m++)
      #pragma unroll
      for (int n=0;n<4;n++)
        acc[m][n] = __builtin_amdgcn_mfma_f32_16x16x32_bf16(af[m], bfr[n], acc[m][n], 0,0,0);
    asm volatile("s_waitcnt lgkmcnt(0)" ::: "memory");
    asm volatile("s_barrier" ::: "memory");
    cur ^= 1;
  }
  #undef STAGEW

  // epilogue: 2 strips of 64 rows x 256 cols (32 KB f16 in LDS)
  const int c16 = lane&15, r4 = (lane>>4)*4;
  float bb[4];
  #pragma unroll
  for (int n=0;n<4;n++) bb[n] = bias[n0 + wc + n*16 + c16];
  #pragma unroll
  for (int s=0;s<2;s++){
    __syncthreads();
    if ((w>>2)==s){
      #pragma unroll
      for (int m=0;m<4;m++)
        #pragma unroll
        for (int n=0;n<4;n++)
          #pragma unroll
          for (int j=0;j<4;j++){
            float val = acc[m][n][j] + bb[n];
            if (OUT_MODE==2) val = gelu_f(val);
            const int row = m*16 + r4 + j;
            const int col = (wc + n*16 + c16) ^ (((row>>2)&3)<<4);
            smem[row*256 + col] = f2b(val);
          }
    }
    __syncthreads();
    if (OUT_MODE==3 && n0 >= 1024){
      // V features: write vt[(b*8+h)*64+d][s] transposed from the LDS tile.
      const int b_    = (m0 + s*64) >> 9;
      const int sbase = (m0 + s*64) & 511;
      const int f = t & 255, half = t >> 8;
      const int fg = (n0 - 1024) + f;
      u16* vrow = vtout + (((size_t)(b_*NH + (fg>>6)))*DHEAD + (fg&63))*SEQ + sbase + half*32;
      #pragma unroll
      for (int cth=0; cth<4; cth++){
        u16x8 val;
        #pragma unroll
        for (int j=0;j<8;j++){
          const int row = half*32 + cth*8 + j;
          val[j] = smem[row*256 + (f ^ (((row>>2)&3)<<4))];
        }
        *(u16x8*)(vrow + cth*8) = val;
      }
    } else {
      #pragma unroll
      for (int i=0;i<4;i++){
        const int lrow = i*16 + (t>>5), colr = (t&31)*8;
        u16x8 vv = *(const u16x8*)(smem + lrow*256 + (colr ^ (((lrow>>2)&3)<<4)));
        *(u16x8*)(Cout + (size_t)(m0 + s*64 + lrow)*N + n0 + colr) = vv;
      }
    }
  }
}

// ---------------- GEMM 256x128 (512 thr, 8 waves): C = A * Bt^T + bias ----------------
// Transpose-role clone of gemm_bt_wide for the N=512 GEMMs (O-proj, FF2).
// Waves 4 rows x 2 cols of 64x64 quadrants; BK=32; counted vmcnt(3) pipeline.
template<int OUT_MODE>
__global__ __launch_bounds__(512) void gemm_bt_tall(
    const u16* __restrict__ A, const u16* __restrict__ Bt,
    const float* __restrict__ bias, u16* __restrict__ Cout,
    int M, int N, int K)
{
  __shared__ u16 smem[24576];   // 2 bufs x (lA[256][32]=16KB + lB[128][32]=8KB) = 48 KB
  const int t = threadIdx.x;
  const int w = t>>6, lane = t&63;

  const int gx = gridDim.x;
  const int id = blockIdx.y*gx + blockIdx.x;
  const int cpx = (gx*gridDim.y) >> 3;
  const int nid = (id & 7)*cpx + (id >> 3);
  const int m0 = (nid / gx)*256, n0 = (nid % gx)*128;

  const int wr = (w>>1)*64, wc = (w&1)*64;

  f32x4 acc[4][4];
  #pragma unroll
  for (int m=0;m<4;m++)
    #pragma unroll
    for (int n=0;n<4;n++) acc[m][n] = f32x4{0.f,0.f,0.f,0.f};

  const int srow = t>>2;
  const int scol = (((t&3) ^ ((srow>>1)&3)))*8;
  const size_t aBase = (size_t)(m0 + srow)*K + scol;
  const size_t bBase = (size_t)(n0 + srow)*K + scol;
  const size_t arstep = (size_t)128*K;    // A rows 128..255 (same XOR: 128%8==0)
  const int dstw = w*512;

  #define STAGET(buf, k0) do{                                      \
    u16* base_ = smem + (buf)*12288;                               \
    gll16(A  + aBase + (k0),           base_ + dstw);              \
    gll16(A  + aBase + arstep + (k0),  base_ + 4096 + dstw);       \
    gll16(Bt + bBase + (k0),           base_ + 8192 + dstw);       \
  }while(0)

  const int g = lane>>4, r16 = lane&15;
  const int chunkoff = ((g ^ ((r16>>1)&3))<<3);

  STAGET(0, 0);
  int cur = 0;
  for (int k0=0; k0<K; k0+=32){
    if (k0+32 < K){
      STAGET(cur^1, k0+32);
      asm volatile("s_waitcnt vmcnt(3)" ::: "memory");   // buf[cur]'s 3 loads done; 3 in flight
    } else {
      asm volatile("s_waitcnt vmcnt(0)" ::: "memory");
    }
    asm volatile("s_barrier" ::: "memory");
    const u16* lA = smem + cur*12288;           // [256][32]
    const u16* lB = lA + 8192;                  // [128][32]
    bf16x8 af[4], bfr[4];
    #pragma unroll
    for (int m=0;m<4;m++) af[m]  = *(const bf16x8*)(lA + (wr+m*16+r16)*32 + chunkoff);
    #pragma unroll
    for (int n=0;n<4;n++) bfr[n] = *(const bf16x8*)(lB + (wc+n*16+r16)*32 + chunkoff);
    #pragma unroll
    for (int m=0;m<4;m++)
      #pragma unroll
      for (int n=0;n<4;n++)
        acc[m][n] = __builtin_amdgcn_mfma_f32_16x16x32_bf16(af[m], bfr[n], acc[m][n], 0,0,0);
    asm volatile("s_waitcnt lgkmcnt(0)" ::: "memory");
    asm volatile("s_barrier" ::: "memory");
    cur ^= 1;
  }
  #undef STAGET

  // epilogue: 4 strips of 64 rows x 128 cols (16 KB u16 in LDS each)
  const int c16 = lane&15, r4 = (lane>>4)*4;
  float bb[4];
  #pragma unroll
  for (int n=0;n<4;n++) bb[n] = bias[n0 + wc + n*16 + c16];
  #pragma unroll
  for (int s=0;s<4;s++){
    __syncthreads();
    if ((w>>1)==s){
      #pragma unroll
      for (int m=0;m<4;m++)
        #pragma unroll
        for (int n=0;n<4;n++)
          #pragma unroll
          for (int j=0;j<4;j++){
            float val = acc[m][n][j] + bb[n];
            if (OUT_MODE==2) val = gelu_f(val);
            const int row = m*16 + r4 + j;
            const int col = (wc + n*16 + c16) ^ (((row>>2)&3)<<4);
            smem[row*128 + col] = f2b(val);
          }
    }
    __syncthreads();
    #pragma unroll
    for (int i=0;i<2;i++){
      const int ch = i*512 + t;
      const int lrow = ch>>4, colr = (ch&15)*8;
      u16x8 vv = *(const u16x8*)(smem + lrow*128 + (colr ^ (((lrow>>2)&3)<<4)));
      *(u16x8*)(Cout + (size_t)(m0 + s*64 + lrow)*N + n0 + colr) = vv;
    }
  }
}

// ---------------- FUSED attention, swapped-operand S^T + BLOCKED scores layout ----------------
template<int ADDP, int WRITES>
__global__ __launch_bounds__(256) void fused_attn(
    const u16* __restrict__ qkv, const u16* __restrict__ vt,
    u16* __restrict__ sc, u16* __restrict__ outp)
{
  __shared__ u16 smem[20480];        // 40KB: lQ[64*64]@0 | lK0@4096 | lK1@12288 (u16 idx)
  u16* lQ = smem;
  const int t=threadIdx.x, w=t>>6, lane=t&63;
  const int g = lane>>4, r16 = lane&15;

  const int dd = blockIdx.x;
  const int c  = dd&7;
  const int j_ = dd>>3;
  const int qb = j_&7;
  const int bh = (j_>>3)*8 + c;      // bijective; all qb of one bh share dd%8 (same XCD)
  const int b = bh>>3, h = bh&7;
  const int q0 = qb*64;

  const int srow = t>>3;
  const int schunk = (t&7) ^ (srow&7);
  const u16* qp = qkv + h*DHEAD;     // ld = 1536
  const u16* kp = qkv + DMODEL + h*DHEAD;
  const size_t qBase = (size_t)(b*SEQ + q0 + srow)*LDQKV + (size_t)(schunk*8);
  const size_t kRow0 = (size_t)(b*SEQ + srow)*LDQKV + (size_t)(schunk*8);

  // stage Q (64 rows) + K tile 0 (128 rows)
  #pragma unroll
  for (int r=0;r<2;r++)
    gll16(qp + qBase + (size_t)(r*32)*LDQKV, lQ + r*2048 + w*512);
  #pragma unroll
  for (int r=0;r<4;r++)
    gll16(kp + kRow0 + (size_t)(r*32)*LDQKV, smem + 4096 + r*2048 + w*512);
  __syncthreads();

  // blocked scores base for this (bh, qb, wave): + kt*16384 per k-tile
  u16* sblk = sc + ((((size_t)bh*8 + qb)*4)*4 + w)*2048 + lane*4;
  const u16* vtp = vt + (size_t)bh*DHEAD*SEQ;

  bf16x8 ones;
  #pragma unroll
  for (int j=0;j<8;j++) ones[j] = (__bf16)1.0f;

  f32x4 pvacc[4][4], rs[4];
  #pragma unroll
  for (int nf=0;nf<4;nf++){
    rs[nf] = f32x4{0.f,0.f,0.f,0.f};
    #pragma unroll
    for (int nd=0;nd<4;nd++) pvacc[nf][nd] = f32x4{0.f,0.f,0.f,0.f};
  }

  #pragma unroll
  for (int kt=0; kt<4; kt++){
    const int cur = 4096 + (kt&1)*8192;
    const int nxt = 4096 + ((kt+1)&1)*8192;
    const int ktw = kt*128 + w*32;
    u16* skt = sblk + (size_t)kt*16384;      // 4 waves x 8 frags x 256 per kt

    // ---- hoisted global loads: S_old fragments + V fragments ----
    u16x4 sold[2][4];
    if (ADDP){
      #pragma unroll
      for (int mf=0;mf<2;mf++)
        #pragma unroll
        for (int nf=0;nf<4;nf++)
          sold[mf][nf] = *(const u16x4*)(skt + (mf*4+nf)*256);
    }
    u16x4 vfrag[4][2];
    #pragma unroll
    for (int nd=0;nd<4;nd++){
      const u16* vr = vtp + (size_t)(nd*16+r16)*SEQ + ktw + g*4;
      vfrag[nd][0] = *(const u16x4*)(vr);
      vfrag[nd][1] = *(const u16x4*)(vr + 16);
    }
    // stage next K tile now (completes by the end-of-kt counted barrier)
    if (kt<3){
      const size_t kB = kRow0 + (size_t)((kt+1)*128)*LDQKV;
      #pragma unroll
      for (int r=0;r<4;r++)
        gll16(kp + kB + (size_t)(r*32)*LDQKV, smem + nxt + r*2048 + w*512);
    }
    __builtin_amdgcn_sched_barrier(0);   // pin VMEM issue order: gll16 before stores

    // S^T MFMAs: acc[mf][nf]; lane -> S[q=nf*16+r16][k=w*32+mf*16+g*4+j]
    f32x4 acc[2][4];
    #pragma unroll
    for (int mf=0;mf<2;mf++)
      #pragma unroll
      for (int nf=0;nf<4;nf++) acc[mf][nf] = f32x4{0.f,0.f,0.f,0.f};
    #pragma unroll
    for (int ks=0; ks<2; ks++){
      bf16x8 af[2], bfq[4];
      #pragma unroll
      for (int mf=0;mf<2;mf++){
        const int row = w*32 + mf*16 + r16;
        af[mf] = *(const bf16x8*)(smem + cur + row*64 + (((ks*4+g)^(row&7))<<3));
      }
      #pragma unroll
      for (int nf=0;nf<4;nf++){
        const int row = nf*16 + r16;
        bfq[nf] = *(const bf16x8*)(lQ + row*64 + (((ks*4+g)^(row&7))<<3));
      }
      #pragma unroll
      for (int mf=0;mf<2;mf++)
        #pragma unroll
        for (int nf=0;nf<4;nf++)
          acc[mf][nf] = __builtin_amdgcn_mfma_f32_16x16x32_bf16(af[mf], bfq[nf], acc[mf][nf], 0,0,0);
    }

    // epilogue in registers: scale, +S_old, store S_new (coalesced), exp -> pe; rowsum
    bf16x8 pe[4];
    #pragma unroll
    for (int nf=0;nf<4;nf++){
      u16x8 pk;
      #pragma unroll
      for (int mf=0;mf<2;mf++){
        float v[4]; u16x4 sn;
        #pragma unroll
        for (int j=0;j<4;j++){
          v[j] = acc[mf][nf][j]*0.125f;
          if (ADDP) v[j] += b2f(sold[mf][nf][j]);
          if (WRITES) sn[j] = f2b(v[j]);
          pk[mf*4+j] = f2b(__expf(v[j]));
        }
        if (WRITES)
          *(u16x4*)(skt + (mf*4+nf)*256) = sn;
      }
      pe[nf] = __builtin_bit_cast(bf16x8, pk);
      rs[nf] = __builtin_amdgcn_mfma_f32_16x16x32_bf16(pe[nf], ones, rs[nf], 0,0,0);
    }

    // PV: B from the hoisted vfrag (same per-lane k-mapping as pe's slots)
    #pragma unroll
    for (int nd=0;nd<4;nd++){
      u16x8 vv;
      #pragma unroll
      for (int j=0;j<4;j++){ vv[j] = vfrag[nd][0][j]; vv[4+j] = vfrag[nd][1][j]; }
      bf16x8 vb = __builtin_bit_cast(bf16x8, vv);
      #pragma unroll
      for (int nf=0;nf<4;nf++)
        pvacc[nf][nd] = __builtin_amdgcn_mfma_f32_16x16x32_bf16(pe[nf], vb, pvacc[nf][nd], 0,0,0);
    }

    // counted barrier: K-staging complete; S_new stores may remain in flight
    asm volatile("s_waitcnt lgkmcnt(0)" ::: "memory");
    if (kt<3){
      if (WRITES) asm volatile("s_waitcnt vmcnt(8)" ::: "memory");
      else        asm volatile("s_waitcnt vmcnt(0)" ::: "memory");
    }
    asm volatile("s_barrier" ::: "memory");
  }

  // ---- cross-wave reduce: padded [64][68] f32, two parallel trees, 2 barriers ----
  float* bufA = (float*)smem;              // [64][68] = 17,408 B
  float* bufB = bufA + 64*68;              // [64][68] = 17,408 B
  float* bufR = bufB + 64*68;              // [4][64]  =  1,024 B  (total 35,840 <= 40,960)
  if (r16 == 0){
    #pragma unroll
    for (int nf=0;nf<4;nf++)
      #pragma unroll
      for (int j=0;j<4;j++)
        bufR[w*64 + nf*16 + g*4 + j] = rs[nf][j];
  }
  if (w < 2){
    float* dst = (w==0) ? bufA : bufB;
    #pragma unroll
    for (int nf=0;nf<4;nf++)
      #pragma unroll
      for (int nd=0;nd<4;nd++)
        #pragma unroll
        for (int j=0;j<4;j++)
          dst[(nf*16+g*4+j)*68 + nd*16+r16] = pvacc[nf][nd][j];
  }
  __syncthreads();
  if (w >= 2){
    float* dst = (w==2) ? bufA : bufB;
    #pragma unroll
    for (int nf=0;nf<4;nf++)
      #pragma unroll
      for (int nd=0;nd<4;nd++)
        #pragma unroll
        for (int j=0;j<4;j++)
          dst[(nf*16+g*4+j)*68 + nd*16+r16] += pvacc[nf][nd][j];
  }
  __syncthreads();
  // final: thread t -> q = t>>2, d-base = (t&3)*16 ; O = (A+B)*inv
  {
    const int q = t>>2, db = (t&3)*16;
    const float tot = bufR[q] + bufR[64+q] + bufR[128+q] + bufR[192+q];
    const float inv = 1.0f/tot;
    const float* ra = bufA + q*68 + db;
    const float* rb = bufB + q*68 + db;
    u16* ob = outp + ((size_t)(b*SEQ + q0 + q)*NH + h)*DHEAD + db;
    u16x8 o0, o1;
    #pragma unroll
    for (int j=0;j<8;j++) o0[j] = f2b((ra[j]   + rb[j]  )*inv);
    #pragma unroll
    for (int j=0;j<8;j++) o1[j] = f2b((ra[8+j] + rb[8+j])*inv);
    *(u16x8*)(ob)     = o0;
    *(u16x8*)(ob + 8) = o1;
  }
}

// ---------------- LayerNorm(xb + proj) -> xb (bf16) [+ f32 out for final layer] ----------------
template<int WF>
__global__ __launch_bounds__(256) void ln_k(
    const u16* __restrict__ xin, const u16* __restrict__ proj,
    const float* __restrict__ g, const float* __restrict__ beta,
    u16* __restrict__ xb, float* __restrict__ fout)
{
  const int row = blockIdx.x*4 + (threadIdx.x>>6);
  const int lane = threadIdx.x & 63;
  const size_t base = (size_t)row*DMODEL + lane*8;
  u16x8 a = *(const u16x8*)(xin + base);
  u16x8 p = *(const u16x8*)(proj + base);
  float v[8];
  #pragma unroll
  for (int j=0;j<8;j++) v[j] = b2f(a[j]) + b2f(p[j]);
  float s = 0.f;
  #pragma unroll
  for (int j=0;j<8;j++) s += v[j];
  s = wred_sum(s);
  const float mean = s * (1.0f/DMODEL);
  float qv = 0.f;
  #pragma unroll
  for (int j=0;j<8;j++){ float d = v[j]-mean; qv += d*d; }
  qv = wred_sum(qv);
  const float rstd = rsqrtf(qv*(1.0f/DMODEL) + 1e-5f);
  const int c = lane*8;
  float o[8]; u16x8 ob;
  #pragma unroll
  for (int j=0;j<8;j++){
    o[j] = (v[j]-mean)*rstd*g[c+j] + beta[c+j];
    ob[j] = f2b(o[j]);
  }
  *(u16x8*)(xb + base) = ob;
  if (WF){
    *(float4*)(fout + base)     = make_float4(o[0],o[1],o[2],o[3]);
    *(float4*)(fout + base + 4) = make_float4(o[4],o[5],o[6],o[7]);
  }
}

// ---------------- weight transpose+convert: fp32 [l,K,N] -> bf16 [l,N,K] ----------------
__global__ __launch_bounds__(256) void wt_conv(
    const float* __restrict__ Win, u16* __restrict__ Wout,
    int K, int N, long outLstride)
{
  __shared__ float T[32][33];
  const int t = threadIdx.x;
  const int tx = t&31, ty = t>>5;
  const int n0 = blockIdx.x*32, k0 = blockIdx.y*32, l = blockIdx.z;
  const float* W = Win + (size_t)l*K*N;
  u16* O = Wout + (size_t)l*outLstride;
  #pragma unroll
  for (int i=0;i<4;i++)
    T[ty+i*8][tx] = W[(size_t)(k0+ty+i*8)*N + n0 + tx];
  __syncthreads();
  #pragma unroll
  for (int i=0;i<4;i++){
    const int nn = ty + i*8;
    O[(size_t)(n0+nn)*K + k0 + tx] = f2b(T[tx][nn]);
  }
}

__global__ void bias_concat(const float* __restrict__ bq, const float* __restrict__ bk,
                            const float* __restrict__ bv, float* __restrict__ out)
{
  const int i = blockIdx.x*256 + threadIdx.x;   // NL*1536 = 6144
  if (i >= NL*LDQKV) return;
  const int l = i / LDQKV, c = i % LDQKV;
  float v;
  if (c < DMODEL)        v = bq[l*DMODEL + c];
  else if (c < 2*DMODEL) v = bk[l*DMODEL + c - DMODEL];
  else                   v = bv[l*DMODEL + c - 2*DMODEL];
  out[i] = v;
}

__global__ void conv_src(const float* __restrict__ src, u16* __restrict__ xb)
{
  const int i = blockIdx.x*256 + threadIdx.x;   // NTOK*DMODEL/4 threads
  float4 v = ((const float4*)src)[i];
  u16x4 bb; bb[0]=f2b(v.x); bb[1]=f2b(v.y); bb[2]=f2b(v.z); bb[3]=f2b(v.w);
  *(u16x4*)(xb + (size_t)i*4) = bb;
}

__global__ void diag_fill(float* __restrict__ o, int n, float v){
  int i = blockIdx.x*256 + threadIdx.x;
  if (i < n) o[i] = v;
}

extern "C" void kernel_launch(void* const* d_in, const int* in_sizes, int n_in,
                              void* d_out, int out_size, void* d_ws, size_t ws_size,
                              hipStream_t stream)
{
  (void)in_sizes; (void)n_in;
  const float* src = (const float*)d_in[0];
  const float* Wq  = (const float*)d_in[1];
  const float* bq  = (const float*)d_in[2];
  const float* Wk  = (const float*)d_in[3];
  const float* bk  = (const float*)d_in[4];
  const float* Wv  = (const float*)d_in[5];
  const float* bv  = (const float*)d_in[6];
  const float* Wo  = (const float*)d_in[7];
  const float* bo  = (const float*)d_in[8];
  const float* ln1g= (const float*)d_in[9];
  const float* ln1b= (const float*)d_in[10];
  const float* ln2g= (const float*)d_in[11];
  const float* ln2b= (const float*)d_in[12];
  const float* Wf1 = (const float*)d_in[13];
  const float* bf1 = (const float*)d_in[14];
  const float* Wf2 = (const float*)d_in[15];
  const float* bf2 = (const float*)d_in[16];

  // workspace layout (bytes); total NEEDED = 260,071,424 (~248 MiB)
  const size_t NEEDED = 260071424ull;
  if (ws_size < NEEDED){
    diag_fill<<<(out_size+255)/256, 256, 0, stream>>>((float*)d_out, out_size,
                                                      (float)(ws_size >> 20));
    return;
  }
  char* ws = (char*)d_ws;
  u16*  xb     = (u16*)(ws + 0);                 //  16,777,216  [16384][512] bf16 residual
  u16*  qkv    = (u16*)(ws + 16777216);          //  50,331,648  [16384][1536]
  u16*  attn_o = (u16*)(ws + 16777216);          //  16,777,216  alias qkv (dead when written)
  u16*  hbuf   = (u16*)(ws + 16777216);          //  67,108,864  alias qkv+vt (dead during FF)
  u16*  vt     = (u16*)(ws + 67108864);          //  16,777,216  [B,H,DK,S]
  u16*  scores = (u16*)(ws + 83886080);          // 134,217,728  blocked fragment layout
  u16*  proj   = (u16*)(ws + 218103808);         //  16,777,216  [16384][512] bf16
  u16*  wqkvT  = (u16*)(ws + 234881024);         //   6,291,456  [L][1536][512]
  u16*  woT    = (u16*)(ws + 241172480);         //   2,097,152  [L][512][512]
  u16*  wf1T   = (u16*)(ws + 243269632);         //   8,388,608  [L][2048][512]
  u16*  wf2T   = (u16*)(ws + 251658240);         //   8,388,608  [L][512][2048]
  float* qkvb  = (float*)(ws + 260046848);       //      24,576  [L][1536]

  dim3 blk(256);
  dim3 blkw(512);

  // weight prep (per call; cheap)
  wt_conv<<<dim3(16,16,4),blk,0,stream>>>(Wq, wqkvT,                  DMODEL, DMODEL, (long)LDQKV*DMODEL);
  wt_conv<<<dim3(16,16,4),blk,0,stream>>>(Wk, wqkvT + DMODEL*DMODEL,  DMODEL, DMODEL, (long)LDQKV*DMODEL);
  wt_conv<<<dim3(16,16,4),blk,0,stream>>>(Wv, wqkvT + 2*DMODEL*DMODEL,DMODEL, DMODEL, (long)LDQKV*DMODEL);
  wt_conv<<<dim3(16,16,4),blk,0,stream>>>(Wo, woT,  DMODEL, DMODEL, (long)DMODEL*DMODEL);
  wt_conv<<<dim3(64,16,4),blk,0,stream>>>(Wf1, wf1T, DMODEL, FFDIM, (long)FFDIM*DMODEL);
  wt_conv<<<dim3(16,64,4),blk,0,stream>>>(Wf2, wf2T, FFDIM, DMODEL, (long)DMODEL*FFDIM);
  bias_concat<<<24,blk,0,stream>>>(bq,bk,bv,qkvb);
  conv_src<<<8192,blk,0,stream>>>(src, xb);

  for (int l=0; l<NL; l++){
    // fused QKV projection (wide 128x256 tiles); V-feature blocks write vt directly
    gemm_bt_wide<3><<<dim3(6,128),blkw,0,stream>>>(xb, wqkvT + (size_t)l*LDQKV*DMODEL,
                                                   qkvb + l*LDQKV, qkv, vt, NTOK, LDQKV, DMODEL);
    // fused scores + softmax + PV (swapped-operand S^T, blocked scores layout)
    if (l==0)
      fused_attn<0,1><<<dim3(2048),blk,0,stream>>>(qkv, vt, scores, attn_o);
    else if (l<NL-1)
      fused_attn<1,1><<<dim3(2048),blk,0,stream>>>(qkv, vt, scores, attn_o);
    else
      fused_attn<1,0><<<dim3(2048),blk,0,stream>>>(qkv, vt, scores, attn_o);
    // O projection -> proj (bf16)  (tall 256x128 tiles)
    gemm_bt_tall<0><<<dim3(4,64),blkw,0,stream>>>(attn_o, woT + (size_t)l*DMODEL*DMODEL,
                                                  bo + l*DMODEL, proj, NTOK, DMODEL, DMODEL);
    ln_k<0><<<NTOK/4,blk,0,stream>>>(xb, proj, ln1g + l*DMODEL, ln1b + l*DMODEL, xb, nullptr);
    // FF1 + GELU -> bf16  (wide 128x256 tiles)
    gemm_bt_wide<2><<<dim3(8,128),blkw,0,stream>>>(xb, wf1T + (size_t)l*FFDIM*DMODEL,
                                                   bf1 + l*FFDIM, hbuf, nullptr, NTOK, FFDIM, DMODEL);
    // FF2 -> proj (bf16)  (tall 256x128 tiles)
    gemm_bt_tall<0><<<dim3(4,64),blkw,0,stream>>>(hbuf, wf2T + (size_t)l*DMODEL*FFDIM,
                                                  bf2 + l*DMODEL, proj, NTOK, DMODEL, FFDIM);
    if (l==NL-1)
      ln_k<1><<<NTOK/4,blk,0,stream>>>(xb, proj, ln2g + l*DMODEL, ln2b + l*DMODEL, xb, (float*)d_out);
    else
      ln_k<0><<<NTOK/4,blk,0,stream>>>(xb, proj, ln2g + l*DMODEL, ln2b + l*DMODEL, xb, nullptr);
  }
}

// Round 17
// 1012.449 us; speedup vs baseline: 1.0078x; 1.0078x over previous
//
#include <hip/hip_runtime.h>
#include <hip/hip_bf16.h>

// TSTEncoder: L=4 layers, D=512, H=8, FF=2048, B=32, S=512, DK=64
// Residual attention (raw scores carried across layers), post-norm, GELU.

#define NL 4
#define DMODEL 512
#define NH 8
#define FFDIM 2048
#define BATCH 32
#define SEQ 512
#define DHEAD 64
#define NTOK (BATCH*SEQ)          // 16384
#define LDQKV (3*DMODEL)          // 1536

typedef unsigned short u16;
typedef __bf16 bf16x8 __attribute__((ext_vector_type(8)));
typedef float f32x4 __attribute__((ext_vector_type(4)));
typedef unsigned short u16x8 __attribute__((ext_vector_type(8)));
typedef unsigned short u16x4 __attribute__((ext_vector_type(4)));

// f32 -> bf16 RNE via native cast (compiler emits v_cvt_pk_bf16_f32 for pairs)
__device__ __forceinline__ u16 f2b(float f){
  return __builtin_bit_cast(u16, (__bf16)f);
}
__device__ __forceinline__ float b2f(u16 h){
  return __builtin_bit_cast(float, ((unsigned)h)<<16);
}
__device__ __forceinline__ void gll16(const void* g, void* l){
  __builtin_amdgcn_global_load_lds((__attribute__((address_space(1))) void*)(g),
                                   (__attribute__((address_space(3))) void*)(l), 16, 0, 0);
}
__device__ __forceinline__ float wred_sum(float v){
  #pragma unroll
  for (int off=32; off; off>>=1) v += __shfl_xor(v, off, 64);
  return v;
}
// GELU, tanh form: 0.5v(1+tanh(0.79788456(v+0.044715v^3))) = v - v/(e^{2y}+1)
__device__ __forceinline__ float gelu_f(float v){
  float y = 0.79788456080286536f*(v + 0.044715f*v*v*v);
  float t = __expf(2.0f*y);
  return v - v/(t + 1.0f);
}

// ---------------- GEMM 128x128 (256 thr): C = A * Bt^T + bias ----------------
// BK=32, double-buffered LDS, T4 counted-vmcnt pipeline.
// OUT_MODE: 0 = bf16 store, 2 = GELU then bf16 store,
//           4 = bf16 store of (acc + bias + Res[row][col])  (residual fused)
template<int OUT_MODE>
__global__ __launch_bounds__(256) void gemm_bt(
    const u16* __restrict__ A, const u16* __restrict__ Bt,
    const float* __restrict__ bias, u16* __restrict__ Cout,
    const u16* __restrict__ Res,
    int M, int N, int K)
{
  __shared__ u16 smem[16384];   // 2 bufs x (lA[128][32] + lB[128][32]) = 32 KB
  const int t = threadIdx.x;
  const int w = t>>6, lane = t&63;

  // XCD-chunked bijective swizzle (all grids divisible by 8)
  const int gx = gridDim.x;
  const int id = blockIdx.y*gx + blockIdx.x;
  const int cpx = (gx*gridDim.y) >> 3;
  const int nid = (id & 7)*cpx + (id >> 3);
  const int m0 = (nid / gx)*128, n0 = (nid % gx)*128;

  const int wr = (w>>1)*64, wc = (w&1)*64;

  f32x4 acc[4][4];
  #pragma unroll
  for (int m=0;m<4;m++)
    #pragma unroll
    for (int n=0;n<4;n++) acc[m][n] = f32x4{0.f,0.f,0.f,0.f};

  const int srow = t>>2;
  const int scol = (((t&3) ^ ((srow>>1)&3)))*8;
  const size_t aBase = (size_t)(m0 + srow)*K + scol;
  const size_t bBase = (size_t)(n0 + srow)*K + scol;
  const size_t rstep = (size_t)64*K;
  const int dstw = w*512;

  #define STAGE(buf, k0) do{                                       \
    u16* base_ = smem + (buf)*8192;                                \
    gll16(A  + aBase + (k0),          base_ + dstw);               \
    gll16(A  + aBase + rstep + (k0),  base_ + 2048 + dstw);        \
    gll16(Bt + bBase + (k0),          base_ + 4096 + dstw);        \
    gll16(Bt + bBase + rstep + (k0),  base_ + 6144 + dstw);        \
  }while(0)

  const int g = lane>>4, r16 = lane&15;
  const int chunkoff = ((g ^ ((r16>>1)&3))<<3);   // read-side XOR undoes source swizzle

  STAGE(0, 0);
  int cur = 0;
  for (int k0=0; k0<K; k0+=32){
    if (k0+32 < K){
      STAGE(cur^1, k0+32);
      asm volatile("s_waitcnt vmcnt(4)" ::: "memory");   // buf[cur] done; 4 stay in flight
    } else {
      asm volatile("s_waitcnt vmcnt(0)" ::: "memory");   // tail: drain the last tile
    }
    asm volatile("s_barrier" ::: "memory");
    const u16* lA = smem + cur*8192;
    const u16* lB = lA + 4096;
    bf16x8 af[4], bfr[4];
    #pragma unroll
    for (int m=0;m<4;m++) af[m]  = *(const bf16x8*)(lA + (wr+m*16+r16)*32 + chunkoff);
    #pragma unroll
    for (int n=0;n<4;n++) bfr[n] = *(const bf16x8*)(lB + (wc+n*16+r16)*32 + chunkoff);
    #pragma unroll
    for (int m=0;m<4;m++)
      #pragma unroll
      for (int n=0;n<4;n++)
        acc[m][n] = __builtin_amdgcn_mfma_f32_16x16x32_bf16(af[m], bfr[n], acc[m][n], 0,0,0);
    asm volatile("s_waitcnt lgkmcnt(0)" ::: "memory");   // my ds_reads of buf[cur] complete
    asm volatile("s_barrier" ::: "memory");              // all waves done reading buf[cur]
    cur ^= 1;
  }
  #undef STAGE

  // epilogue: 2 strips of 64 rows; stage u16 in LDS (swizzled) then coalesced 16B stores
  const int c16 = lane&15, r4 = (lane>>4)*4;
  float bb[4];
  #pragma unroll
  for (int n=0;n<4;n++) bb[n] = bias[n0 + wc + n*16 + c16];
  #pragma unroll
  for (int s=0;s<2;s++){
    __syncthreads();
    if ((w>>1)==s){
      #pragma unroll
      for (int m=0;m<4;m++)
        #pragma unroll
        for (int n=0;n<4;n++)
          #pragma unroll
          for (int j=0;j<4;j++){
            float val = acc[m][n][j] + bb[n];
            if (OUT_MODE==2) val = gelu_f(val);
            const int row = m*16 + r4 + j;
            const int col = (wc + n*16 + c16) ^ (((row>>2)&3)<<4);
            smem[row*128 + col] = f2b(val);
          }
    }
    __syncthreads();
    #pragma unroll
    for (int i=0;i<4;i++){
      const int lrow = i*16 + (t>>4), colr = (t&15)*8;
      u16x8 vv = *(const u16x8*)(smem + lrow*128 + (colr ^ (((lrow>>2)&3)<<4)));
      const size_t gidx = (size_t)(m0 + s*64 + lrow)*N + n0 + colr;
      if (OUT_MODE==4){
        u16x8 rv = *(const u16x8*)(Res + gidx);
        #pragma unroll
        for (int j=0;j<8;j++) vv[j] = f2b(b2f(vv[j]) + b2f(rv[j]));
      }
      *(u16x8*)(Cout + gidx) = vv;
    }
  }
}

// ---------------- GEMM 128x256 (512 thr, 8 waves): C = A * Bt^T + bias ----------------
template<int OUT_MODE>
__global__ __launch_bounds__(512) void gemm_bt_wide(
    const u16* __restrict__ A, const u16* __restrict__ Bt,
    const float* __restrict__ bias, u16* __restrict__ Cout,
    int M, int N, int K)
{
  __shared__ u16 smem[24576];   // 2 bufs x (lA[128][32]=8KB + lB[256][32]=16KB) = 48 KB
  const int t = threadIdx.x;
  const int w = t>>6, lane = t&63;

  const int gx = gridDim.x;
  const int id = blockIdx.y*gx + blockIdx.x;
  const int cpx = (gx*gridDim.y) >> 3;
  const int nid = (id & 7)*cpx + (id >> 3);
  const int m0 = (nid / gx)*128, n0 = (nid % gx)*256;

  const int wr = (w>>2)*64, wc = (w&3)*64;

  f32x4 acc[4][4];
  #pragma unroll
  for (int m=0;m<4;m++)
    #pragma unroll
    for (int n=0;n<4;n++) acc[m][n] = f32x4{0.f,0.f,0.f,0.f};

  const int srow = t>>2;
  const int scol = (((t&3) ^ ((srow>>1)&3)))*8;
  const size_t aBase = (size_t)(m0 + srow)*K + scol;
  const size_t bBase = (size_t)(n0 + srow)*K + scol;
  const size_t brstep = (size_t)128*K;    // B rows 128..255 (same XOR: 128%8==0)
  const int dstw = w*512;

  #define STAGEW(buf, k0) do{                                      \
    u16* base_ = smem + (buf)*12288;                               \
    gll16(A  + aBase + (k0),           base_ + dstw);              \
    gll16(Bt + bBase + (k0),           base_ + 4096 + dstw);       \
    gll16(Bt + bBase + brstep + (k0),  base_ + 8192 + dstw);       \
  }while(0)

  const int g = lane>>4, r16 = lane&15;
  const int chunkoff = ((g ^ ((r16>>1)&3))<<3);

  STAGEW(0, 0);
  int cur = 0;
  for (int k0=0; k0<K; k0+=32){
    if (k0+32 < K){
      STAGEW(cur^1, k0+32);
      asm volatile("s_waitcnt vmcnt(3)" ::: "memory");   // buf[cur]'s 3 loads done; 3 in flight
    } else {
      asm volatile("s_waitcnt vmcnt(0)" ::: "memory");
    }
    asm volatile("s_barrier" ::: "memory");
    const u16* lA = smem + cur*12288;
    const u16* lB = lA + 4096;
    bf16x8 af[4], bfr[4];
    #pragma unroll
    for (int m=0;m<4;m++) af[m]  = *(const bf16x8*)(lA + (wr+m*16+r16)*32 + chunkoff);
    #pragma unroll
    for (int n=0;n<4;n++) bfr[n] = *(const bf16x8*)(lB + (wc+n*16+r16)*32 + chunkoff);
    #pragma unroll
    for (int m=0;m<4;m++)
      #pragma unroll
      for (int n=0;n<4;n++)
        acc[m][n] = __builtin_amdgcn_mfma_f32_16x16x32_bf16(af[m], bfr[n], acc[m][n], 0,0,0);
    asm volatile("s_waitcnt lgkmcnt(0)" ::: "memory");
    asm volatile("s_barrier" ::: "memory");
    cur ^= 1;
  }
  #undef STAGEW

  // epilogue: 2 strips of 64 rows x 256 cols (32 KB f16 in LDS), coalesced 16B stores
  const int c16 = lane&15, r4 = (lane>>4)*4;
  float bb[4];
  #pragma unroll
  for (int n=0;n<4;n++) bb[n] = bias[n0 + wc + n*16 + c16];
  #pragma unroll
  for (int s=0;s<2;s++){
    __syncthreads();
    if ((w>>2)==s){
      #pragma unroll
      for (int m=0;m<4;m++)
        #pragma unroll
        for (int n=0;n<4;n++)
          #pragma unroll
          for (int j=0;j<4;j++){
            float val = acc[m][n][j] + bb[n];
            if (OUT_MODE==2) val = gelu_f(val);
            const int row = m*16 + r4 + j;
            const int col = (wc + n*16 + c16) ^ (((row>>2)&3)<<4);
            smem[row*256 + col] = f2b(val);
          }
    }
    __syncthreads();
    #pragma unroll
    for (int i=0;i<4;i++){
      const int lrow = i*16 + (t>>5), colr = (t&31)*8;
      u16x8 vv = *(const u16x8*)(smem + lrow*256 + (colr ^ (((lrow>>2)&3)<<4)));
      *(u16x8*)(Cout + (size_t)(m0 + s*64 + lrow)*N + n0 + colr) = vv;
    }
  }
}

// ---------------- V transpose: qkv v-slice [b,s,h,d] -> vt [b,h,d,s] ----------------
__global__ __launch_bounds__(256) void transpose_v(
    const u16* __restrict__ qkv, u16* __restrict__ vt)
{
  __shared__ u16 T[64*33];
  const int t = threadIdx.x;
  const int s0 = blockIdx.x*32;
  const int bh = blockIdx.y;
  const int b = bh >> 3, h = bh & 7;
  const u16* v = qkv + 2*DMODEL + h*DHEAD;
  #pragma unroll
  for (int i=0;i<8;i++){
    int idx = i*256 + t;
    int sl = idx >> 6, d = idx & 63;
    T[d*33 + sl] = v[(size_t)(b*SEQ + s0 + sl)*LDQKV + d];
  }
  __syncthreads();
  u16* o = vt + (size_t)bh*DHEAD*SEQ;
  #pragma unroll
  for (int i=0;i<8;i++){
    int idx = i*256 + t;
    int d = idx >> 5, sl = idx & 31;
    o[(size_t)d*SEQ + s0 + sl] = T[d*33 + sl];
  }
}

// ---------------- FUSED attention, swapped-operand S^T + BLOCKED scores layout ----------------
// All per-k-tile global loads (S_old fragments, V fragments) hoisted to the TOP of the
// iteration, and next-K staging issued before the MFMA phase -> max latency overlap.
template<int ADDP, int WRITES>
__global__ __launch_bounds__(256) void fused_attn(
    const u16* __restrict__ qkv, const u16* __restrict__ vt,
    u16* __restrict__ sc, u16* __restrict__ outp)
{
  __shared__ u16 smem[20480];        // 40KB: lQ[64*64]@0 | lK0@4096 | lK1@12288 (u16 idx)
  u16* lQ = smem;
  const int t=threadIdx.x, w=t>>6, lane=t&63;
  const int g = lane>>4, r16 = lane&15;

  const int dd = blockIdx.x;
  const int c  = dd&7;
  const int j_ = dd>>3;
  const int qb = j_&7;
  const int bh = (j_>>3)*8 + c;      // bijective; all qb of one bh share dd%8 (same XCD)
  const int b = bh>>3, h = bh&7;
  const int q0 = qb*64;

  const int srow = t>>3;
  const int schunk = (t&7) ^ (srow&7);
  const u16* qp = qkv + h*DHEAD;     // ld = 1536
  const u16* kp = qkv + DMODEL + h*DHEAD;
  const size_t qBase = (size_t)(b*SEQ + q0 + srow)*LDQKV + (size_t)(schunk*8);
  const size_t kRow0 = (size_t)(b*SEQ + srow)*LDQKV + (size_t)(schunk*8);

  // stage Q (64 rows) + K tile 0 (128 rows)
  #pragma unroll
  for (int r=0;r<2;r++)
    gll16(qp + qBase + (size_t)(r*32)*LDQKV, lQ + r*2048 + w*512);
  #pragma unroll
  for (int r=0;r<4;r++)
    gll16(kp + kRow0 + (size_t)(r*32)*LDQKV, smem + 4096 + r*2048 + w*512);
  __syncthreads();

  // blocked scores base for this (bh, qb, wave): + kt*16384 per k-tile
  u16* sblk = sc + ((((size_t)bh*8 + qb)*4)*4 + w)*2048 + lane*4;
  const u16* vtp = vt + (size_t)bh*DHEAD*SEQ;

  bf16x8 ones;
  #pragma unroll
  for (int j=0;j<8;j++) ones[j] = (__bf16)1.0f;

  f32x4 pvacc[4][4], rs[4];
  #pragma unroll
  for (int nf=0;nf<4;nf++){
    rs[nf] = f32x4{0.f,0.f,0.f,0.f};
    #pragma unroll
    for (int nd=0;nd<4;nd++) pvacc[nf][nd] = f32x4{0.f,0.f,0.f,0.f};
  }

  #pragma unroll
  for (int kt=0; kt<4; kt++){
    const int cur = 4096 + (kt&1)*8192;
    const int nxt = 4096 + ((kt+1)&1)*8192;
    const int ktw = kt*128 + w*32;
    u16* skt = sblk + (size_t)kt*16384;      // 4 waves x 8 frags x 256 per kt

    // ---- hoisted global loads: S_old fragments + V fragments ----
    u16x4 sold[2][4];
    if (ADDP){
      #pragma unroll
      for (int mf=0;mf<2;mf++)
        #pragma unroll
        for (int nf=0;nf<4;nf++)
          sold[mf][nf] = *(const u16x4*)(skt + (mf*4+nf)*256);
    }
    u16x4 vfrag[4][2];
    #pragma unroll
    for (int nd=0;nd<4;nd++){
      const u16* vr = vtp + (size_t)(nd*16+r16)*SEQ + ktw + g*4;
      vfrag[nd][0] = *(const u16x4*)(vr);
      vfrag[nd][1] = *(const u16x4*)(vr + 16);
    }
    // stage next K tile now (drained by the end-of-kt __syncthreads)
    if (kt<3){
      const size_t kB = kRow0 + (size_t)((kt+1)*128)*LDQKV;
      #pragma unroll
      for (int r=0;r<4;r++)
        gll16(kp + kB + (size_t)(r*32)*LDQKV, smem + nxt + r*2048 + w*512);
    }

    // S^T MFMAs: acc[mf][nf]; lane -> S[q=nf*16+r16][k=w*32+mf*16+g*4+j]
    f32x4 acc[2][4];
    #pragma unroll
    for (int mf=0;mf<2;mf++)
      #pragma unroll
      for (int nf=0;nf<4;nf++) acc[mf][nf] = f32x4{0.f,0.f,0.f,0.f};
    #pragma unroll
    for (int ks=0; ks<2; ks++){
      bf16x8 af[2], bfq[4];
      #pragma unroll
      for (int mf=0;mf<2;mf++){
        const int row = w*32 + mf*16 + r16;
        af[mf] = *(const bf16x8*)(smem + cur + row*64 + (((ks*4+g)^(row&7))<<3));
      }
      #pragma unroll
      for (int nf=0;nf<4;nf++){
        const int row = nf*16 + r16;
        bfq[nf] = *(const bf16x8*)(lQ + row*64 + (((ks*4+g)^(row&7))<<3));
      }
      #pragma unroll
      for (int mf=0;mf<2;mf++)
        #pragma unroll
        for (int nf=0;nf<4;nf++)
          acc[mf][nf] = __builtin_amdgcn_mfma_f32_16x16x32_bf16(af[mf], bfq[nf], acc[mf][nf], 0,0,0);
    }

    // epilogue in registers: scale, +S_old, store S_new (coalesced), exp -> pe; rowsum
    bf16x8 pe[4];
    #pragma unroll
    for (int nf=0;nf<4;nf++){
      u16x8 pk;
      #pragma unroll
      for (int mf=0;mf<2;mf++){
        float v[4]; u16x4 sn;
        #pragma unroll
        for (int j=0;j<4;j++){
          v[j] = acc[mf][nf][j]*0.125f;
          if (ADDP) v[j] += b2f(sold[mf][nf][j]);
          if (WRITES) sn[j] = f2b(v[j]);
          pk[mf*4+j] = f2b(__expf(v[j]));
        }
        if (WRITES)
          *(u16x4*)(skt + (mf*4+nf)*256) = sn;
      }
      pe[nf] = __builtin_bit_cast(bf16x8, pk);
      rs[nf] = __builtin_amdgcn_mfma_f32_16x16x32_bf16(pe[nf], ones, rs[nf], 0,0,0);
    }

    // PV: B from the hoisted vfrag (same per-lane k-mapping as pe's slots)
    #pragma unroll
    for (int nd=0;nd<4;nd++){
      u16x8 vv;
      #pragma unroll
      for (int j=0;j<4;j++){ vv[j] = vfrag[nd][0][j]; vv[4+j] = vfrag[nd][1][j]; }
      bf16x8 vb = __builtin_bit_cast(bf16x8, vv);
      #pragma unroll
      for (int nf=0;nf<4;nf++)
        pvacc[nf][nd] = __builtin_amdgcn_mfma_f32_16x16x32_bf16(pe[nf], vb, pvacc[nf][nd], 0,0,0);
    }

    __syncthreads();   // next-K staged & everyone done reading buf[cur]
  }

  // ---- cross-wave reduce: padded [64][68] f32, two parallel trees, 2 barriers ----
  float* bufA = (float*)smem;              // [64][68] = 17,408 B
  float* bufB = bufA + 64*68;              // [64][68] = 17,408 B
  float* bufR = bufB + 64*68;              // [4][64]  =  1,024 B  (total 35,840 <= 40,960)
  if (r16 == 0){
    #pragma unroll
    for (int nf=0;nf<4;nf++)
      #pragma unroll
      for (int j=0;j<4;j++)
        bufR[w*64 + nf*16 + g*4 + j] = rs[nf][j];
  }
  if (w < 2){
    float* dst = (w==0) ? bufA : bufB;
    #pragma unroll
    for (int nf=0;nf<4;nf++)
      #pragma unroll
      for (int nd=0;nd<4;nd++)
        #pragma unroll
        for (int j=0;j<4;j++)
          dst[(nf*16+g*4+j)*68 + nd*16+r16] = pvacc[nf][nd][j];
  }
  __syncthreads();
  if (w >= 2){
    float* dst = (w==2) ? bufA : bufB;
    #pragma unroll
    for (int nf=0;nf<4;nf++)
      #pragma unroll
      for (int nd=0;nd<4;nd++)
        #pragma unroll
        for (int j=0;j<4;j++)
          dst[(nf*16+g*4+j)*68 + nd*16+r16] += pvacc[nf][nd][j];
  }
  __syncthreads();
  // final: thread t -> q = t>>2, d-base = (t&3)*16 ; O = (A+B)*inv
  {
    const int q = t>>2, db = (t&3)*16;
    const float tot = bufR[q] + bufR[64+q] + bufR[128+q] + bufR[192+q];
    const float inv = 1.0f/tot;
    const float* ra = bufA + q*68 + db;
    const float* rb = bufB + q*68 + db;
    u16* ob = outp + ((size_t)(b*SEQ + q0 + q)*NH + h)*DHEAD + db;
    u16x8 o0, o1;
    #pragma unroll
    for (int j=0;j<8;j++) o0[j] = f2b((ra[j]   + rb[j]  )*inv);
    #pragma unroll
    for (int j=0;j<8;j++) o1[j] = f2b((ra[8+j] + rb[8+j])*inv);
    *(u16x8*)(ob)     = o0;
    *(u16x8*)(ob + 8) = o1;
  }
}

// ---------------- LayerNorm(vin) -> xb (bf16) [+ f32 out for final layer] ----------------
// vin already holds x + delta (residual fused into the producing GEMM's epilogue).
template<int WF>
__global__ __launch_bounds__(256) void ln_k(
    const u16* __restrict__ vin,
    const float* __restrict__ g, const float* __restrict__ beta,
    u16* __restrict__ xb, float* __restrict__ fout)
{
  const int row = blockIdx.x*4 + (threadIdx.x>>6);
  const int lane = threadIdx.x & 63;
  const size_t base = (size_t)row*DMODEL + lane*8;
  u16x8 p = *(const u16x8*)(vin + base);
  float v[8];
  #pragma unroll
  for (int j=0;j<8;j++) v[j] = b2f(p[j]);
  float s = 0.f;
  #pragma unroll
  for (int j=0;j<8;j++) s += v[j];
  s = wred_sum(s);
  const float mean = s * (1.0f/DMODEL);
  float qv = 0.f;
  #pragma unroll
  for (int j=0;j<8;j++){ float d = v[j]-mean; qv += d*d; }
  qv = wred_sum(qv);
  const float rstd = rsqrtf(qv*(1.0f/DMODEL) + 1e-5f);
  const int c = lane*8;
  float o[8]; u16x8 ob;
  #pragma unroll
  for (int j=0;j<8;j++){
    o[j] = (v[j]-mean)*rstd*g[c+j] + beta[c+j];
    ob[j] = f2b(o[j]);
  }
  *(u16x8*)(xb + base) = ob;
  if (WF){
    *(float4*)(fout + base)     = make_float4(o[0],o[1],o[2],o[3]);
    *(float4*)(fout + base + 4) = make_float4(o[4],o[5],o[6],o[7]);
  }
}

// ---------------- weight transpose+convert: fp32 [l,K,N] -> bf16 [l,N,K] ----------------
__global__ __launch_bounds__(256) void wt_conv(
    const float* __restrict__ Win, u16* __restrict__ Wout,
    int K, int N, long outLstride)
{
  __shared__ float T[32][33];
  const int t = threadIdx.x;
  const int tx = t&31, ty = t>>5;
  const int n0 = blockIdx.x*32, k0 = blockIdx.y*32, l = blockIdx.z;
  const float* W = Win + (size_t)l*K*N;
  u16* O = Wout + (size_t)l*outLstride;
  #pragma unroll
  for (int i=0;i<4;i++)
    T[ty+i*8][tx] = W[(size_t)(k0+ty+i*8)*N + n0 + tx];
  __syncthreads();
  #pragma unroll
  for (int i=0;i<4;i++){
    const int nn = ty + i*8;
    O[(size_t)(n0+nn)*K + k0 + tx] = f2b(T[tx][nn]);
  }
}

__global__ void bias_concat(const float* __restrict__ bq, const float* __restrict__ bk,
                            const float* __restrict__ bv, float* __restrict__ out)
{
  const int i = blockIdx.x*256 + threadIdx.x;   // NL*1536 = 6144
  if (i >= NL*LDQKV) return;
  const int l = i / LDQKV, c = i % LDQKV;
  float v;
  if (c < DMODEL)        v = bq[l*DMODEL + c];
  else if (c < 2*DMODEL) v = bk[l*DMODEL + c - DMODEL];
  else                   v = bv[l*DMODEL + c - 2*DMODEL];
  out[i] = v;
}

__global__ void conv_src(const float* __restrict__ src, u16* __restrict__ xb)
{
  const int i = blockIdx.x*256 + threadIdx.x;   // NTOK*DMODEL/4 threads
  float4 v = ((const float4*)src)[i];
  u16x4 bb; bb[0]=f2b(v.x); bb[1]=f2b(v.y); bb[2]=f2b(v.z); bb[3]=f2b(v.w);
  *(u16x4*)(xb + (size_t)i*4) = bb;
}

__global__ void diag_fill(float* __restrict__ o, int n, float v){
  int i = blockIdx.x*256 + threadIdx.x;
  if (i < n) o[i] = v;
}

extern "C" void kernel_launch(void* const* d_in, const int* in_sizes, int n_in,
                              void* d_out, int out_size, void* d_ws, size_t ws_size,
                              hipStream_t stream)
{
  (void)in_sizes; (void)n_in;
  const float* src = (const float*)d_in[0];
  const float* Wq  = (const float*)d_in[1];
  const float* bq  = (const float*)d_in[2];
  const float* Wk  = (const float*)d_in[3];
  const float* bk  = (const float*)d_in[4];
  const float* Wv  = (const float*)d_in[5];
  const float* bv  = (const float*)d_in[6];
  const float* Wo  = (const float*)d_in[7];
  const float* bo  = (const float*)d_in[8];
  const float* ln1g= (const float*)d_in[9];
  const float* ln1b= (const float*)d_in[10];
  const float* ln2g= (const float*)d_in[11];
  const float* ln2b= (const float*)d_in[12];
  const float* Wf1 = (const float*)d_in[13];
  const float* bf1 = (const float*)d_in[14];
  const float* Wf2 = (const float*)d_in[15];
  const float* bf2 = (const float*)d_in[16];

  // workspace layout (bytes); total NEEDED = 260,071,424 (~248 MiB)
  const size_t NEEDED = 260071424ull;
  if (ws_size < NEEDED){
    diag_fill<<<(out_size+255)/256, 256, 0, stream>>>((float*)d_out, out_size,
                                                      (float)(ws_size >> 20));
    return;
  }
  char* ws = (char*)d_ws;
  u16*  xb     = (u16*)(ws + 0);                 //  16,777,216  [16384][512] bf16 residual
  u16*  qkv    = (u16*)(ws + 16777216);          //  50,331,648  [16384][1536]
  u16*  attn_o = (u16*)(ws + 16777216);          //  16,777,216  alias qkv (dead when written)
  u16*  hbuf   = (u16*)(ws + 16777216);          //  67,108,864  alias qkv+vt (dead during FF)
  u16*  vt     = (u16*)(ws + 67108864);          //  16,777,216  [B,H,DK,S]
  u16*  scores = (u16*)(ws + 83886080);          // 134,217,728  blocked fragment layout
  u16*  proj   = (u16*)(ws + 218103808);         //  16,777,216  [16384][512] bf16
  u16*  wqkvT  = (u16*)(ws + 234881024);         //   6,291,456  [L][1536][512]
  u16*  woT    = (u16*)(ws + 241172480);         //   2,097,152  [L][512][512]
  u16*  wf1T   = (u16*)(ws + 243269632);         //   8,388,608  [L][2048][512]
  u16*  wf2T   = (u16*)(ws + 251658240);         //   8,388,608  [L][512][2048]
  float* qkvb  = (float*)(ws + 260046848);       //      24,576  [L][1536]

  dim3 blk(256);
  dim3 blkw(512);

  // weight prep (per call; cheap)
  wt_conv<<<dim3(16,16,4),blk,0,stream>>>(Wq, wqkvT,                  DMODEL, DMODEL, (long)LDQKV*DMODEL);
  wt_conv<<<dim3(16,16,4),blk,0,stream>>>(Wk, wqkvT + DMODEL*DMODEL,  DMODEL, DMODEL, (long)LDQKV*DMODEL);
  wt_conv<<<dim3(16,16,4),blk,0,stream>>>(Wv, wqkvT + 2*DMODEL*DMODEL,DMODEL, DMODEL, (long)LDQKV*DMODEL);
  wt_conv<<<dim3(16,16,4),blk,0,stream>>>(Wo, woT,  DMODEL, DMODEL, (long)DMODEL*DMODEL);
  wt_conv<<<dim3(64,16,4),blk,0,stream>>>(Wf1, wf1T, DMODEL, FFDIM, (long)FFDIM*DMODEL);
  wt_conv<<<dim3(16,64,4),blk,0,stream>>>(Wf2, wf2T, FFDIM, DMODEL, (long)DMODEL*FFDIM);
  bias_concat<<<24,blk,0,stream>>>(bq,bk,bv,qkvb);
  conv_src<<<8192,blk,0,stream>>>(src, xb);

  for (int l=0; l<NL; l++){
    // fused QKV projection: [16384,512] x [1536,512]^T  (wide 128x256 tiles)
    gemm_bt_wide<0><<<dim3(6,128),blkw,0,stream>>>(xb, wqkvT + (size_t)l*LDQKV*DMODEL,
                                                   qkvb + l*LDQKV, qkv, NTOK, LDQKV, DMODEL);
    transpose_v<<<dim3(16,BATCH*NH),blk,0,stream>>>(qkv, vt);
    // fused scores + softmax + PV (swapped-operand S^T, blocked scores layout)
    if (l==0)
      fused_attn<0,1><<<dim3(2048),blk,0,stream>>>(qkv, vt, scores, attn_o);
    else if (l<NL-1)
      fused_attn<1,1><<<dim3(2048),blk,0,stream>>>(qkv, vt, scores, attn_o);
    else
      fused_attn<1,0><<<dim3(2048),blk,0,stream>>>(qkv, vt, scores, attn_o);
    // O projection + residual(xb) -> proj (bf16)
    gemm_bt<4><<<dim3(4,128),blk,0,stream>>>(attn_o, woT + (size_t)l*DMODEL*DMODEL,
                                             bo + l*DMODEL, proj, xb, NTOK, DMODEL, DMODEL);
    ln_k<0><<<NTOK/4,blk,0,stream>>>(proj, ln1g + l*DMODEL, ln1b + l*DMODEL, xb, nullptr);
    // FF1 + GELU -> bf16  (wide 128x256 tiles)
    gemm_bt_wide<2><<<dim3(8,128),blkw,0,stream>>>(xb, wf1T + (size_t)l*FFDIM*DMODEL,
                                                   bf1 + l*FFDIM, hbuf, NTOK, FFDIM, DMODEL);
    // FF2 + residual(xb) -> proj (bf16)
    gemm_bt<4><<<dim3(4,128),blk,0,stream>>>(hbuf, wf2T + (size_t)l*DMODEL*FFDIM,
                                             bf2 + l*DMODEL, proj, xb, NTOK, DMODEL, FFDIM);
    if (l==NL-1)
      ln_k<1><<<NTOK/4,blk,0,stream>>>(proj, ln2g + l*DMODEL, ln2b + l*DMODEL, xb, (float*)d_out);
    else
      ln_k<0><<<NTOK/4,blk,0,stream>>>(proj, ln2g + l*DMODEL, ln2b + l*DMODEL, xb, nullptr);
  }
}

// Round 18
// 998.004 us; speedup vs baseline: 1.0224x; 1.0145x over previous
//
#include <hip/hip_runtime.h>
#include <hip/hip_bf16.h>

// TSTEncoder: L=4 layers, D=512, H=8, FF=2048, B=32, S=512, DK=64
// Residual attention (raw scores carried across layers), post-norm, GELU.
// SELECTED CONFIG (best measured, round 14: 1000.3 us, absmax 0.078):
//  - wide 128x256 GEMM for QKV/FF1, narrow 128x128 for O-proj/FF2
//  - separate transpose_v; two-input LayerNorm
//  - fused_attn: swapped-operand S^T, blocked scores layout, hoisted loads,
//    plain end-of-k-tile barrier (counted store-barrier measured neutral)

#define NL 4
#define DMODEL 512
#define NH 8
#define FFDIM 2048
#define BATCH 32
#define SEQ 512
#define DHEAD 64
#define NTOK (BATCH*SEQ)          // 16384
#define LDQKV (3*DMODEL)          // 1536

typedef unsigned short u16;
typedef __bf16 bf16x8 __attribute__((ext_vector_type(8)));
typedef float f32x4 __attribute__((ext_vector_type(4)));
typedef unsigned short u16x8 __attribute__((ext_vector_type(8)));
typedef unsigned short u16x4 __attribute__((ext_vector_type(4)));

// f32 -> bf16 RNE via native cast (compiler emits v_cvt_pk_bf16_f32 for pairs)
__device__ __forceinline__ u16 f2b(float f){
  return __builtin_bit_cast(u16, (__bf16)f);
}
__device__ __forceinline__ float b2f(u16 h){
  return __builtin_bit_cast(float, ((unsigned)h)<<16);
}
__device__ __forceinline__ void gll16(const void* g, void* l){
  __builtin_amdgcn_global_load_lds((__attribute__((address_space(1))) void*)(g),
                                   (__attribute__((address_space(3))) void*)(l), 16, 0, 0);
}
__device__ __forceinline__ float wred_sum(float v){
  #pragma unroll
  for (int off=32; off; off>>=1) v += __shfl_xor(v, off, 64);
  return v;
}
// GELU, tanh form: 0.5v(1+tanh(0.79788456(v+0.044715v^3))) = v - v/(e^{2y}+1)
__device__ __forceinline__ float gelu_f(float v){
  float y = 0.79788456080286536f*(v + 0.044715f*v*v*v);
  float t = __expf(2.0f*y);
  return v - v/(t + 1.0f);
}

// ---------------- GEMM 128x128 (256 thr): C = A * Bt^T + bias ----------------
// BK=32, double-buffered LDS, T4 counted-vmcnt pipeline.
// OUT_MODE: 0 = bf16 store, 2 = GELU then bf16 store
template<int OUT_MODE>
__global__ __launch_bounds__(256) void gemm_bt(
    const u16* __restrict__ A, const u16* __restrict__ Bt,
    const float* __restrict__ bias, u16* __restrict__ Cout,
    int M, int N, int K)
{
  __shared__ u16 smem[16384];   // 2 bufs x (lA[128][32] + lB[128][32]) = 32 KB
  const int t = threadIdx.x;
  const int w = t>>6, lane = t&63;

  // XCD-chunked bijective swizzle (all grids divisible by 8)
  const int gx = gridDim.x;
  const int id = blockIdx.y*gx + blockIdx.x;
  const int cpx = (gx*gridDim.y) >> 3;
  const int nid = (id & 7)*cpx + (id >> 3);
  const int m0 = (nid / gx)*128, n0 = (nid % gx)*128;

  const int wr = (w>>1)*64, wc = (w&1)*64;

  f32x4 acc[4][4];
  #pragma unroll
  for (int m=0;m<4;m++)
    #pragma unroll
    for (int n=0;n<4;n++) acc[m][n] = f32x4{0.f,0.f,0.f,0.f};

  const int srow = t>>2;
  const int scol = (((t&3) ^ ((srow>>1)&3)))*8;
  const size_t aBase = (size_t)(m0 + srow)*K + scol;
  const size_t bBase = (size_t)(n0 + srow)*K + scol;
  const size_t rstep = (size_t)64*K;
  const int dstw = w*512;

  #define STAGE(buf, k0) do{                                       \
    u16* base_ = smem + (buf)*8192;                                \
    gll16(A  + aBase + (k0),          base_ + dstw);               \
    gll16(A  + aBase + rstep + (k0),  base_ + 2048 + dstw);        \
    gll16(Bt + bBase + (k0),          base_ + 4096 + dstw);        \
    gll16(Bt + bBase + rstep + (k0),  base_ + 6144 + dstw);        \
  }while(0)

  const int g = lane>>4, r16 = lane&15;
  const int chunkoff = ((g ^ ((r16>>1)&3))<<3);   // read-side XOR undoes source swizzle

  STAGE(0, 0);
  int cur = 0;
  for (int k0=0; k0<K; k0+=32){
    if (k0+32 < K){
      STAGE(cur^1, k0+32);
      asm volatile("s_waitcnt vmcnt(4)" ::: "memory");   // buf[cur] done; 4 stay in flight
    } else {
      asm volatile("s_waitcnt vmcnt(0)" ::: "memory");   // tail: drain the last tile
    }
    asm volatile("s_barrier" ::: "memory");
    const u16* lA = smem + cur*8192;
    const u16* lB = lA + 4096;
    bf16x8 af[4], bfr[4];
    #pragma unroll
    for (int m=0;m<4;m++) af[m]  = *(const bf16x8*)(lA + (wr+m*16+r16)*32 + chunkoff);
    #pragma unroll
    for (int n=0;n<4;n++) bfr[n] = *(const bf16x8*)(lB + (wc+n*16+r16)*32 + chunkoff);
    #pragma unroll
    for (int m=0;m<4;m++)
      #pragma unroll
      for (int n=0;n<4;n++)
        acc[m][n] = __builtin_amdgcn_mfma_f32_16x16x32_bf16(af[m], bfr[n], acc[m][n], 0,0,0);
    asm volatile("s_waitcnt lgkmcnt(0)" ::: "memory");   // my ds_reads of buf[cur] complete
    asm volatile("s_barrier" ::: "memory");              // all waves done reading buf[cur]
    cur ^= 1;
  }
  #undef STAGE

  // epilogue: 2 strips of 64 rows; stage u16 in LDS (swizzled) then coalesced 16B stores
  const int c16 = lane&15, r4 = (lane>>4)*4;
  float bb[4];
  #pragma unroll
  for (int n=0;n<4;n++) bb[n] = bias[n0 + wc + n*16 + c16];
  #pragma unroll
  for (int s=0;s<2;s++){
    __syncthreads();
    if ((w>>1)==s){
      #pragma unroll
      for (int m=0;m<4;m++)
        #pragma unroll
        for (int n=0;n<4;n++)
          #pragma unroll
          for (int j=0;j<4;j++){
            float val = acc[m][n][j] + bb[n];
            if (OUT_MODE==2) val = gelu_f(val);
            const int row = m*16 + r4 + j;
            const int col = (wc + n*16 + c16) ^ (((row>>2)&3)<<4);
            smem[row*128 + col] = f2b(val);
          }
    }
    __syncthreads();
    #pragma unroll
    for (int i=0;i<4;i++){
      const int lrow = i*16 + (t>>4), colr = (t&15)*8;
      u16x8 vv = *(const u16x8*)(smem + lrow*128 + (colr ^ (((lrow>>2)&3)<<4)));
      *(u16x8*)(Cout + (size_t)(m0 + s*64 + lrow)*N + n0 + colr) = vv;
    }
  }
}

// ---------------- GEMM 128x256 (512 thr, 8 waves): C = A * Bt^T + bias ----------------
template<int OUT_MODE>
__global__ __launch_bounds__(512) void gemm_bt_wide(
    const u16* __restrict__ A, const u16* __restrict__ Bt,
    const float* __restrict__ bias, u16* __restrict__ Cout,
    int M, int N, int K)
{
  __shared__ u16 smem[24576];   // 2 bufs x (lA[128][32]=8KB + lB[256][32]=16KB) = 48 KB
  const int t = threadIdx.x;
  const int w = t>>6, lane = t&63;

  const int gx = gridDim.x;
  const int id = blockIdx.y*gx + blockIdx.x;
  const int cpx = (gx*gridDim.y) >> 3;
  const int nid = (id & 7)*cpx + (id >> 3);
  const int m0 = (nid / gx)*128, n0 = (nid % gx)*256;

  const int wr = (w>>2)*64, wc = (w&3)*64;

  f32x4 acc[4][4];
  #pragma unroll
  for (int m=0;m<4;m++)
    #pragma unroll
    for (int n=0;n<4;n++) acc[m][n] = f32x4{0.f,0.f,0.f,0.f};

  const int srow = t>>2;
  const int scol = (((t&3) ^ ((srow>>1)&3)))*8;
  const size_t aBase = (size_t)(m0 + srow)*K + scol;
  const size_t bBase = (size_t)(n0 + srow)*K + scol;
  const size_t brstep = (size_t)128*K;    // B rows 128..255 (same XOR: 128%8==0)
  const int dstw = w*512;

  #define STAGEW(buf, k0) do{                                      \
    u16* base_ = smem + (buf)*12288;                               \
    gll16(A  + aBase + (k0),           base_ + dstw);              \
    gll16(Bt + bBase + (k0),           base_ + 4096 + dstw);       \
    gll16(Bt + bBase + brstep + (k0),  base_ + 8192 + dstw);       \
  }while(0)

  const int g = lane>>4, r16 = lane&15;
  const int chunkoff = ((g ^ ((r16>>1)&3))<<3);

  STAGEW(0, 0);
  int cur = 0;
  for (int k0=0; k0<K; k0+=32){
    if (k0+32 < K){
      STAGEW(cur^1, k0+32);
      asm volatile("s_waitcnt vmcnt(3)" ::: "memory");   // buf[cur]'s 3 loads done; 3 in flight
    } else {
      asm volatile("s_waitcnt vmcnt(0)" ::: "memory");
    }
    asm volatile("s_barrier" ::: "memory");
    const u16* lA = smem + cur*12288;
    const u16* lB = lA + 4096;
    bf16x8 af[4], bfr[4];
    #pragma unroll
    for (int m=0;m<4;m++) af[m]  = *(const bf16x8*)(lA + (wr+m*16+r16)*32 + chunkoff);
    #pragma unroll
    for (int n=0;n<4;n++) bfr[n] = *(const bf16x8*)(lB + (wc+n*16+r16)*32 + chunkoff);
    #pragma unroll
    for (int m=0;m<4;m++)
      #pragma unroll
      for (int n=0;n<4;n++)
        acc[m][n] = __builtin_amdgcn_mfma_f32_16x16x32_bf16(af[m], bfr[n], acc[m][n], 0,0,0);
    asm volatile("s_waitcnt lgkmcnt(0)" ::: "memory");
    asm volatile("s_barrier" ::: "memory");
    cur ^= 1;
  }
  #undef STAGEW

  // epilogue: 2 strips of 64 rows x 256 cols (32 KB f16 in LDS), coalesced 16B stores
  const int c16 = lane&15, r4 = (lane>>4)*4;
  float bb[4];
  #pragma unroll
  for (int n=0;n<4;n++) bb[n] = bias[n0 + wc + n*16 + c16];
  #pragma unroll
  for (int s=0;s<2;s++){
    __syncthreads();
    if ((w>>2)==s){
      #pragma unroll
      for (int m=0;m<4;m++)
        #pragma unroll
        for (int n=0;n<4;n++)
          #pragma unroll
          for (int j=0;j<4;j++){
            float val = acc[m][n][j] + bb[n];
            if (OUT_MODE==2) val = gelu_f(val);
            const int row = m*16 + r4 + j;
            const int col = (wc + n*16 + c16) ^ (((row>>2)&3)<<4);
            smem[row*256 + col] = f2b(val);
          }
    }
    __syncthreads();
    #pragma unroll
    for (int i=0;i<4;i++){
      const int lrow = i*16 + (t>>5), colr = (t&31)*8;
      u16x8 vv = *(const u16x8*)(smem + lrow*256 + (colr ^ (((lrow>>2)&3)<<4)));
      *(u16x8*)(Cout + (size_t)(m0 + s*64 + lrow)*N + n0 + colr) = vv;
    }
  }
}

// ---------------- V transpose: qkv v-slice [b,s,h,d] -> vt [b,h,d,s] ----------------
__global__ __launch_bounds__(256) void transpose_v(
    const u16* __restrict__ qkv, u16* __restrict__ vt)
{
  __shared__ u16 T[64*33];
  const int t = threadIdx.x;
  const int s0 = blockIdx.x*32;
  const int bh = blockIdx.y;
  const int b = bh >> 3, h = bh & 7;
  const u16* v = qkv + 2*DMODEL + h*DHEAD;
  #pragma unroll
  for (int i=0;i<8;i++){
    int idx = i*256 + t;
    int sl = idx >> 6, d = idx & 63;
    T[d*33 + sl] = v[(size_t)(b*SEQ + s0 + sl)*LDQKV + d];
  }
  __syncthreads();
  u16* o = vt + (size_t)bh*DHEAD*SEQ;
  #pragma unroll
  for (int i=0;i<8;i++){
    int idx = i*256 + t;
    int d = idx >> 5, sl = idx & 31;
    o[(size_t)d*SEQ + s0 + sl] = T[d*33 + sl];
  }
}

// ---------------- FUSED attention, swapped-operand S^T + BLOCKED scores layout ----------------
// All per-k-tile global loads (S_old fragments, V fragments) hoisted to the TOP of the
// iteration, and next-K staging issued before the MFMA phase -> max latency overlap.
template<int ADDP, int WRITES>
__global__ __launch_bounds__(256) void fused_attn(
    const u16* __restrict__ qkv, const u16* __restrict__ vt,
    u16* __restrict__ sc, u16* __restrict__ outp)
{
  __shared__ u16 smem[20480];        // 40KB: lQ[64*64]@0 | lK0@4096 | lK1@12288 (u16 idx)
  u16* lQ = smem;
  const int t=threadIdx.x, w=t>>6, lane=t&63;
  const int g = lane>>4, r16 = lane&15;

  const int dd = blockIdx.x;
  const int c  = dd&7;
  const int j_ = dd>>3;
  const int qb = j_&7;
  const int bh = (j_>>3)*8 + c;      // bijective; all qb of one bh share dd%8 (same XCD)
  const int b = bh>>3, h = bh&7;
  const int q0 = qb*64;

  const int srow = t>>3;
  const int schunk = (t&7) ^ (srow&7);
  const u16* qp = qkv + h*DHEAD;     // ld = 1536
  const u16* kp = qkv + DMODEL + h*DHEAD;
  const size_t qBase = (size_t)(b*SEQ + q0 + srow)*LDQKV + (size_t)(schunk*8);
  const size_t kRow0 = (size_t)(b*SEQ + srow)*LDQKV + (size_t)(schunk*8);

  // stage Q (64 rows) + K tile 0 (128 rows)
  #pragma unroll
  for (int r=0;r<2;r++)
    gll16(qp + qBase + (size_t)(r*32)*LDQKV, lQ + r*2048 + w*512);
  #pragma unroll
  for (int r=0;r<4;r++)
    gll16(kp + kRow0 + (size_t)(r*32)*LDQKV, smem + 4096 + r*2048 + w*512);
  __syncthreads();

  // blocked scores base for this (bh, qb, wave): + kt*16384 per k-tile
  u16* sblk = sc + ((((size_t)bh*8 + qb)*4)*4 + w)*2048 + lane*4;
  const u16* vtp = vt + (size_t)bh*DHEAD*SEQ;

  bf16x8 ones;
  #pragma unroll
  for (int j=0;j<8;j++) ones[j] = (__bf16)1.0f;

  f32x4 pvacc[4][4], rs[4];
  #pragma unroll
  for (int nf=0;nf<4;nf++){
    rs[nf] = f32x4{0.f,0.f,0.f,0.f};
    #pragma unroll
    for (int nd=0;nd<4;nd++) pvacc[nf][nd] = f32x4{0.f,0.f,0.f,0.f};
  }

  #pragma unroll
  for (int kt=0; kt<4; kt++){
    const int cur = 4096 + (kt&1)*8192;
    const int nxt = 4096 + ((kt+1)&1)*8192;
    const int ktw = kt*128 + w*32;
    u16* skt = sblk + (size_t)kt*16384;      // 4 waves x 8 frags x 256 per kt

    // ---- hoisted global loads: S_old fragments + V fragments (latency covered
    //      by the whole MFMA+epilogue phase) ----
    u16x4 sold[2][4];
    if (ADDP){
      #pragma unroll
      for (int mf=0;mf<2;mf++)
        #pragma unroll
        for (int nf=0;nf<4;nf++)
          sold[mf][nf] = *(const u16x4*)(skt + (mf*4+nf)*256);
    }
    u16x4 vfrag[4][2];
    #pragma unroll
    for (int nd=0;nd<4;nd++){
      const u16* vr = vtp + (size_t)(nd*16+r16)*SEQ + ktw + g*4;
      vfrag[nd][0] = *(const u16x4*)(vr);
      vfrag[nd][1] = *(const u16x4*)(vr + 16);
    }
    // stage next K tile now (drained by the end-of-kt __syncthreads)
    if (kt<3){
      const size_t kB = kRow0 + (size_t)((kt+1)*128)*LDQKV;
      #pragma unroll
      for (int r=0;r<4;r++)
        gll16(kp + kB + (size_t)(r*32)*LDQKV, smem + nxt + r*2048 + w*512);
    }

    // S^T MFMAs: acc[mf][nf]; lane -> S[q=nf*16+r16][k=w*32+mf*16+g*4+j]
    f32x4 acc[2][4];
    #pragma unroll
    for (int mf=0;mf<2;mf++)
      #pragma unroll
      for (int nf=0;nf<4;nf++) acc[mf][nf] = f32x4{0.f,0.f,0.f,0.f};
    #pragma unroll
    for (int ks=0; ks<2; ks++){
      bf16x8 af[2], bfq[4];
      #pragma unroll
      for (int mf=0;mf<2;mf++){
        const int row = w*32 + mf*16 + r16;
        af[mf] = *(const bf16x8*)(smem + cur + row*64 + (((ks*4+g)^(row&7))<<3));
      }
      #pragma unroll
      for (int nf=0;nf<4;nf++){
        const int row = nf*16 + r16;
        bfq[nf] = *(const bf16x8*)(lQ + row*64 + (((ks*4+g)^(row&7))<<3));
      }
      #pragma unroll
      for (int mf=0;mf<2;mf++)
        #pragma unroll
        for (int nf=0;nf<4;nf++)
          acc[mf][nf] = __builtin_amdgcn_mfma_f32_16x16x32_bf16(af[mf], bfq[nf], acc[mf][nf], 0,0,0);
    }

    // epilogue in registers: scale, +S_old, store S_new (coalesced), exp -> pe; rowsum
    bf16x8 pe[4];
    #pragma unroll
    for (int nf=0;nf<4;nf++){
      u16x8 pk;
      #pragma unroll
      for (int mf=0;mf<2;mf++){
        float v[4]; u16x4 sn;
        #pragma unroll
        for (int j=0;j<4;j++){
          v[j] = acc[mf][nf][j]*0.125f;
          if (ADDP) v[j] += b2f(sold[mf][nf][j]);
          if (WRITES) sn[j] = f2b(v[j]);
          pk[mf*4+j] = f2b(__expf(v[j]));
        }
        if (WRITES)
          *(u16x4*)(skt + (mf*4+nf)*256) = sn;
      }
      pe[nf] = __builtin_bit_cast(bf16x8, pk);
      rs[nf] = __builtin_amdgcn_mfma_f32_16x16x32_bf16(pe[nf], ones, rs[nf], 0,0,0);
    }

    // PV: B from the hoisted vfrag (same per-lane k-mapping as pe's slots)
    #pragma unroll
    for (int nd=0;nd<4;nd++){
      u16x8 vv;
      #pragma unroll
      for (int j=0;j<4;j++){ vv[j] = vfrag[nd][0][j]; vv[4+j] = vfrag[nd][1][j]; }
      bf16x8 vb = __builtin_bit_cast(bf16x8, vv);
      #pragma unroll
      for (int nf=0;nf<4;nf++)
        pvacc[nf][nd] = __builtin_amdgcn_mfma_f32_16x16x32_bf16(pe[nf], vb, pvacc[nf][nd], 0,0,0);
    }

    __syncthreads();   // next-K staged & everyone done reading buf[cur]
  }

  // ---- cross-wave reduce: padded [64][68] f32, two parallel trees, 2 barriers ----
  float* bufA = (float*)smem;              // [64][68] = 17,408 B
  float* bufB = bufA + 64*68;              // [64][68] = 17,408 B
  float* bufR = bufB + 64*68;              // [4][64]  =  1,024 B  (total 35,840 <= 40,960)
  if (r16 == 0){
    #pragma unroll
    for (int nf=0;nf<4;nf++)
      #pragma unroll
      for (int j=0;j<4;j++)
        bufR[w*64 + nf*16 + g*4 + j] = rs[nf][j];
  }
  if (w < 2){
    float* dst = (w==0) ? bufA : bufB;
    #pragma unroll
    for (int nf=0;nf<4;nf++)
      #pragma unroll
      for (int nd=0;nd<4;nd++)
        #pragma unroll
        for (int j=0;j<4;j++)
          dst[(nf*16+g*4+j)*68 + nd*16+r16] = pvacc[nf][nd][j];
  }
  __syncthreads();
  if (w >= 2){
    float* dst = (w==2) ? bufA : bufB;
    #pragma unroll
    for (int nf=0;nf<4;nf++)
      #pragma unroll
      for (int nd=0;nd<4;nd++)
        #pragma unroll
        for (int j=0;j<4;j++)
          dst[(nf*16+g*4+j)*68 + nd*16+r16] += pvacc[nf][nd][j];
  }
  __syncthreads();
  // final: thread t -> q = t>>2, d-base = (t&3)*16 ; O = (A+B)*inv
  {
    const int q = t>>2, db = (t&3)*16;
    const float tot = bufR[q] + bufR[64+q] + bufR[128+q] + bufR[192+q];
    const float inv = 1.0f/tot;
    const float* ra = bufA + q*68 + db;
    const float* rb = bufB + q*68 + db;
    u16* ob = outp + ((size_t)(b*SEQ + q0 + q)*NH + h)*DHEAD + db;
    u16x8 o0, o1;
    #pragma unroll
    for (int j=0;j<8;j++) o0[j] = f2b((ra[j]   + rb[j]  )*inv);
    #pragma unroll
    for (int j=0;j<8;j++) o1[j] = f2b((ra[8+j] + rb[8+j])*inv);
    *(u16x8*)(ob)     = o0;
    *(u16x8*)(ob + 8) = o1;
  }
}

// ---------------- LayerNorm(xb + proj) -> xb (bf16) [+ f32 out for final layer] ----------------
template<int WF>
__global__ __launch_bounds__(256) void ln_k(
    const u16* __restrict__ xin, const u16* __restrict__ proj,
    const float* __restrict__ g, const float* __restrict__ beta,
    u16* __restrict__ xb, float* __restrict__ fout)
{
  const int row = blockIdx.x*4 + (threadIdx.x>>6);
  const int lane = threadIdx.x & 63;
  const size_t base = (size_t)row*DMODEL + lane*8;
  u16x8 a = *(const u16x8*)(xin + base);
  u16x8 p = *(const u16x8*)(proj + base);
  float v[8];
  #pragma unroll
  for (int j=0;j<8;j++) v[j] = b2f(a[j]) + b2f(p[j]);
  float s = 0.f;
  #pragma unroll
  for (int j=0;j<8;j++) s += v[j];
  s = wred_sum(s);
  const float mean = s * (1.0f/DMODEL);
  float qv = 0.f;
  #pragma unroll
  for (int j=0;j<8;j++){ float d = v[j]-mean; qv += d*d; }
  qv = wred_sum(qv);
  const float rstd = rsqrtf(qv*(1.0f/DMODEL) + 1e-5f);
  const int c = lane*8;
  float o[8]; u16x8 ob;
  #pragma unroll
  for (int j=0;j<8;j++){
    o[j] = (v[j]-mean)*rstd*g[c+j] + beta[c+j];
    ob[j] = f2b(o[j]);
  }
  *(u16x8*)(xb + base) = ob;
  if (WF){
    *(float4*)(fout + base)     = make_float4(o[0],o[1],o[2],o[3]);
    *(float4*)(fout + base + 4) = make_float4(o[4],o[5],o[6],o[7]);
  }
}

// ---------------- weight transpose+convert: fp32 [l,K,N] -> bf16 [l,N,K] ----------------
__global__ __launch_bounds__(256) void wt_conv(
    const float* __restrict__ Win, u16* __restrict__ Wout,
    int K, int N, long outLstride)
{
  __shared__ float T[32][33];
  const int t = threadIdx.x;
  const int tx = t&31, ty = t>>5;
  const int n0 = blockIdx.x*32, k0 = blockIdx.y*32, l = blockIdx.z;
  const float* W = Win + (size_t)l*K*N;
  u16* O = Wout + (size_t)l*outLstride;
  #pragma unroll
  for (int i=0;i<4;i++)
    T[ty+i*8][tx] = W[(size_t)(k0+ty+i*8)*N + n0 + tx];
  __syncthreads();
  #pragma unroll
  for (int i=0;i<4;i++){
    const int nn = ty + i*8;
    O[(size_t)(n0+nn)*K + k0 + tx] = f2b(T[tx][nn]);
  }
}

__global__ void bias_concat(const float* __restrict__ bq, const float* __restrict__ bk,
                            const float* __restrict__ bv, float* __restrict__ out)
{
  const int i = blockIdx.x*256 + threadIdx.x;   // NL*1536 = 6144
  if (i >= NL*LDQKV) return;
  const int l = i / LDQKV, c = i % LDQKV;
  float v;
  if (c < DMODEL)        v = bq[l*DMODEL + c];
  else if (c < 2*DMODEL) v = bk[l*DMODEL + c - DMODEL];
  else                   v = bv[l*DMODEL + c - 2*DMODEL];
  out[i] = v;
}

__global__ void conv_src(const float* __restrict__ src, u16* __restrict__ xb)
{
  const int i = blockIdx.x*256 + threadIdx.x;   // NTOK*DMODEL/4 threads
  float4 v = ((const float4*)src)[i];
  u16x4 bb; bb[0]=f2b(v.x); bb[1]=f2b(v.y); bb[2]=f2b(v.z); bb[3]=f2b(v.w);
  *(u16x4*)(xb + (size_t)i*4) = bb;
}

__global__ void diag_fill(float* __restrict__ o, int n, float v){
  int i = blockIdx.x*256 + threadIdx.x;
  if (i < n) o[i] = v;
}

extern "C" void kernel_launch(void* const* d_in, const int* in_sizes, int n_in,
                              void* d_out, int out_size, void* d_ws, size_t ws_size,
                              hipStream_t stream)
{
  (void)in_sizes; (void)n_in;
  const float* src = (const float*)d_in[0];
  const float* Wq  = (const float*)d_in[1];
  const float* bq  = (const float*)d_in[2];
  const float* Wk  = (const float*)d_in[3];
  const float* bk  = (const float*)d_in[4];
  const float* Wv  = (const float*)d_in[5];
  const float* bv  = (const float*)d_in[6];
  const float* Wo  = (const float*)d_in[7];
  const float* bo  = (const float*)d_in[8];
  const float* ln1g= (const float*)d_in[9];
  const float* ln1b= (const float*)d_in[10];
  const float* ln2g= (const float*)d_in[11];
  const float* ln2b= (const float*)d_in[12];
  const float* Wf1 = (const float*)d_in[13];
  const float* bf1 = (const float*)d_in[14];
  const float* Wf2 = (const float*)d_in[15];
  const float* bf2 = (const float*)d_in[16];

  // workspace layout (bytes); total NEEDED = 260,071,424 (~248 MiB)
  const size_t NEEDED = 260071424ull;
  if (ws_size < NEEDED){
    diag_fill<<<(out_size+255)/256, 256, 0, stream>>>((float*)d_out, out_size,
                                                      (float)(ws_size >> 20));
    return;
  }
  char* ws = (char*)d_ws;
  u16*  xb     = (u16*)(ws + 0);                 //  16,777,216  [16384][512] bf16 residual
  u16*  qkv    = (u16*)(ws + 16777216);          //  50,331,648  [16384][1536]
  u16*  attn_o = (u16*)(ws + 16777216);          //  16,777,216  alias qkv (dead when written)
  u16*  hbuf   = (u16*)(ws + 16777216);          //  67,108,864  alias qkv+vt (dead during FF)
  u16*  vt     = (u16*)(ws + 67108864);          //  16,777,216  [B,H,DK,S]
  u16*  scores = (u16*)(ws + 83886080);          // 134,217,728  blocked fragment layout
  u16*  proj   = (u16*)(ws + 218103808);         //  16,777,216  [16384][512] bf16
  u16*  wqkvT  = (u16*)(ws + 234881024);         //   6,291,456  [L][1536][512]
  u16*  woT    = (u16*)(ws + 241172480);         //   2,097,152  [L][512][512]
  u16*  wf1T   = (u16*)(ws + 243269632);         //   8,388,608  [L][2048][512]
  u16*  wf2T   = (u16*)(ws + 251658240);         //   8,388,608  [L][512][2048]
  float* qkvb  = (float*)(ws + 260046848);       //      24,576  [L][1536]

  dim3 blk(256);
  dim3 blkw(512);

  // weight prep (per call; cheap)
  wt_conv<<<dim3(16,16,4),blk,0,stream>>>(Wq, wqkvT,                  DMODEL, DMODEL, (long)LDQKV*DMODEL);
  wt_conv<<<dim3(16,16,4),blk,0,stream>>>(Wk, wqkvT + DMODEL*DMODEL,  DMODEL, DMODEL, (long)LDQKV*DMODEL);
  wt_conv<<<dim3(16,16,4),blk,0,stream>>>(Wv, wqkvT + 2*DMODEL*DMODEL,DMODEL, DMODEL, (long)LDQKV*DMODEL);
  wt_conv<<<dim3(16,16,4),blk,0,stream>>>(Wo, woT,  DMODEL, DMODEL, (long)DMODEL*DMODEL);
  wt_conv<<<dim3(64,16,4),blk,0,stream>>>(Wf1, wf1T, DMODEL, FFDIM, (long)FFDIM*DMODEL);
  wt_conv<<<dim3(16,64,4),blk,0,stream>>>(Wf2, wf2T, FFDIM, DMODEL, (long)DMODEL*FFDIM);
  bias_concat<<<24,blk,0,stream>>>(bq,bk,bv,qkvb);
  conv_src<<<8192,blk,0,stream>>>(src, xb);

  for (int l=0; l<NL; l++){
    // fused QKV projection: [16384,512] x [1536,512]^T  (wide 128x256 tiles)
    gemm_bt_wide<0><<<dim3(6,128),blkw,0,stream>>>(xb, wqkvT + (size_t)l*LDQKV*DMODEL,
                                                   qkvb + l*LDQKV, qkv, NTOK, LDQKV, DMODEL);
    transpose_v<<<dim3(16,BATCH*NH),blk,0,stream>>>(qkv, vt);
    // fused scores + softmax + PV (swapped-operand S^T, blocked scores layout)
    if (l==0)
      fused_attn<0,1><<<dim3(2048),blk,0,stream>>>(qkv, vt, scores, attn_o);
    else if (l<NL-1)
      fused_attn<1,1><<<dim3(2048),blk,0,stream>>>(qkv, vt, scores, attn_o);
    else
      fused_attn<1,0><<<dim3(2048),blk,0,stream>>>(qkv, vt, scores, attn_o);
    // O projection -> proj (bf16)
    gemm_bt<0><<<dim3(4,128),blk,0,stream>>>(attn_o, woT + (size_t)l*DMODEL*DMODEL,
                                             bo + l*DMODEL, proj, NTOK, DMODEL, DMODEL);
    ln_k<0><<<NTOK/4,blk,0,stream>>>(xb, proj, ln1g + l*DMODEL, ln1b + l*DMODEL, xb, nullptr);
    // FF1 + GELU -> bf16  (wide 128x256 tiles)
    gemm_bt_wide<2><<<dim3(8,128),blkw,0,stream>>>(xb, wf1T + (size_t)l*FFDIM*DMODEL,
                                                   bf1 + l*FFDIM, hbuf, NTOK, FFDIM, DMODEL);
    // FF2 -> proj (bf16)
    gemm_bt<0><<<dim3(4,128),blk,0,stream>>>(hbuf, wf2T + (size_t)l*DMODEL*FFDIM,
                                             bf2 + l*DMODEL, proj, NTOK, DMODEL, FFDIM);
    if (l==NL-1)
      ln_k<1><<<NTOK/4,blk,0,stream>>>(xb, proj, ln2g + l*DMODEL, ln2b + l*DMODEL, xb, (float*)d_out);
    else
      ln_k<0><<<NTOK/4,blk,0,stream>>>(xb, proj, ln2g + l*DMODEL, ln2b + l*DMODEL, xb, nullptr);
  }
}